// Round 1
// baseline (638.918 us; speedup 1.0000x reference)
//
#include <hip/hip_runtime.h>
#include <hip/hip_bf16.h>

typedef __attribute__((ext_vector_type(8))) short bf16x8;
typedef __attribute__((ext_vector_type(4))) float f32x4;

// ---------------- numerics (must match jnp reference bit-for-bit-ish) ----------------

__device__ __forceinline__ float silu_mul_f(float a, float b) {
  // jax.nn.silu(a) * b = (a * sigmoid(a)) * b
  float s = 1.0f / (1.0f + expf(-a));
  return (a * s) * b;
}

__device__ __forceinline__ float round_e4m3_f(float a) {  // a >= 0
  if (!(a > 0.0f)) return 0.0f;
  float e = floorf(log2f(a));
  e = fminf(fmaxf(e, -6.0f), 8.0f);
  float s = exp2f(e);
  float q = rintf(a / s * 8.0f) * 0.125f * s;  // rintf = round-half-even, matches jnp.round
  return fminf(q, 448.0f);
}

__device__ __forceinline__ float round_e2m1_f(float x) {
  float a = fminf(fabsf(x), 6.0f);
  if (!(a > 0.0f)) return 0.0f;
  float e = fminf(fmaxf(floorf(log2f(a)), 0.0f), 2.0f);
  float step = exp2f(e) * 0.5f;  // 0.5 / 1 / 2
  float q = rintf(a / step) * step;
  q = fminf(q, 6.0f);
  return (x < 0.0f) ? -q : q;
}

// ---------------- pass 0: zero amax scalars ----------------

__global__ void init_scal_kernel(float* scal) {
  if (threadIdx.x < 2) scal[threadIdx.x] = 0.0f;
}

// ---------------- pass 1: global amax of y = silu_mul(x) ----------------

__global__ void silu_amax_kernel(const float* __restrict__ x, float* __restrict__ amaxp,
                                 int hidden) {
  const float* x1 = x + (size_t)blockIdx.x * (size_t)(2 * hidden);
  const float* x2 = x1 + hidden;
  float m = 0.0f;
  int n4 = hidden >> 2;
  for (int c = threadIdx.x; c < n4; c += blockDim.x) {
    float4 v1 = ((const float4*)x1)[c];
    float4 v2 = ((const float4*)x2)[c];
    m = fmaxf(m, fabsf(silu_mul_f(v1.x, v2.x)));
    m = fmaxf(m, fabsf(silu_mul_f(v1.y, v2.y)));
    m = fmaxf(m, fabsf(silu_mul_f(v1.z, v2.z)));
    m = fmaxf(m, fabsf(silu_mul_f(v1.w, v2.w)));
  }
#pragma unroll
  for (int off = 32; off > 0; off >>= 1) m = fmaxf(m, __shfl_xor(m, off));
  __shared__ float sm[4];
  if ((threadIdx.x & 63) == 0) sm[threadIdx.x >> 6] = m;
  __syncthreads();
  if (threadIdx.x == 0) {
    float mm = fmaxf(fmaxf(sm[0], sm[1]), fmaxf(sm[2], sm[3]));
    atomicMax((unsigned int*)amaxp, __float_as_uint(mm));  // values >= 0: uint compare == float compare
  }
}

// ---------------- pass 2: global amax |w| ----------------

__global__ void amax_kernel(const float* __restrict__ p, float* __restrict__ amaxp, int n) {
  const float* row = p + (size_t)blockIdx.x * (size_t)n;
  float m = 0.0f;
  int n4 = n >> 2;
  for (int c = threadIdx.x; c < n4; c += blockDim.x) {
    float4 v = ((const float4*)row)[c];
    m = fmaxf(m, fmaxf(fmaxf(fabsf(v.x), fabsf(v.y)), fmaxf(fabsf(v.z), fabsf(v.w))));
  }
#pragma unroll
  for (int off = 32; off > 0; off >>= 1) m = fmaxf(m, __shfl_xor(m, off));
  __shared__ float sm[4];
  if ((threadIdx.x & 63) == 0) sm[threadIdx.x >> 6] = m;
  __syncthreads();
  if (threadIdx.x == 0) {
    float mm = fmaxf(fmaxf(sm[0], sm[1]), fmaxf(sm[2], sm[3]));
    atomicMax((unsigned int*)amaxp, __float_as_uint(mm));
  }
}

// ---------------- pass 3: quantize activation (recompute silu_mul), dequant to bf16 ----------------

__global__ void quant_act_kernel(const float* __restrict__ x, __hip_bfloat16* __restrict__ A,
                                 const float* __restrict__ amaxp, int hidden) {
  const float gs = 2688.0f / amaxp[0];  // (448*6)/amax
  int row = blockIdx.x;
  const float* x1 = x + (size_t)row * (size_t)(2 * hidden);
  const float* x2 = x1 + hidden;
  int nb = hidden >> 4;
  for (int b = threadIdx.x; b < nb; b += blockDim.x) {
    const float* p1 = x1 + b * 16;
    const float* p2 = x2 + b * 16;
    float y[16];
    float bamax = 0.0f;
#pragma unroll
    for (int j = 0; j < 4; ++j) {
      float4 v1 = *(const float4*)(p1 + 4 * j);
      float4 v2 = *(const float4*)(p2 + 4 * j);
      y[4 * j + 0] = silu_mul_f(v1.x, v2.x);
      y[4 * j + 1] = silu_mul_f(v1.y, v2.y);
      y[4 * j + 2] = silu_mul_f(v1.z, v2.z);
      y[4 * j + 3] = silu_mul_f(v1.w, v2.w);
    }
#pragma unroll
    for (int k = 0; k < 16; ++k) bamax = fmaxf(bamax, fabsf(y[k]));
    float bs = round_e4m3_f(bamax / 6.0f * gs);
    float r = gs / (bs > 0.0f ? bs : 1.0f);
    union { bf16x8 v[2]; unsigned short h[16]; } u;
#pragma unroll
    for (int k = 0; k < 16; ++k) {
      float q = round_e2m1_f(y[k] * r);
      float val = q * bs;  // <= 6 significant bits -> exact in bf16, low 16 fp32 bits are 0
      u.h[k] = (unsigned short)(__float_as_uint(val) >> 16);
    }
    bf16x8* dst = (bf16x8*)(A + (size_t)row * (size_t)hidden + (size_t)b * 16);
    dst[0] = u.v[0];
    dst[1] = u.v[1];
  }
}

// ---------------- pass 4: quantize weight, dequant to bf16 ----------------

__global__ void quant_wt_kernel(const float* __restrict__ w, __hip_bfloat16* __restrict__ B,
                                const float* __restrict__ amaxp, int k) {
  const float gs = 2688.0f / amaxp[0];
  int row = blockIdx.x;
  const float* src = w + (size_t)row * (size_t)k;
  int nb = k >> 4;
  for (int b = threadIdx.x; b < nb; b += blockDim.x) {
    const float* p = src + b * 16;
    float y[16];
    float bamax = 0.0f;
#pragma unroll
    for (int j = 0; j < 4; ++j) {
      float4 v = *(const float4*)(p + 4 * j);
      y[4 * j + 0] = v.x; y[4 * j + 1] = v.y; y[4 * j + 2] = v.z; y[4 * j + 3] = v.w;
    }
#pragma unroll
    for (int kk = 0; kk < 16; ++kk) bamax = fmaxf(bamax, fabsf(y[kk]));
    float bs = round_e4m3_f(bamax / 6.0f * gs);
    float r = gs / (bs > 0.0f ? bs : 1.0f);
    union { bf16x8 v[2]; unsigned short h[16]; } u;
#pragma unroll
    for (int kk = 0; kk < 16; ++kk) {
      float q = round_e2m1_f(y[kk] * r);
      float val = q * bs;
      u.h[kk] = (unsigned short)(__float_as_uint(val) >> 16);
    }
    bf16x8* dst = (bf16x8*)(B + (size_t)row * (size_t)k + (size_t)b * 16);
    dst[0] = u.v[0];
    dst[1] = u.v[1];
  }
}

// ---------------- pass 5: bf16 GEMM  out[m][n] = sum_k A[m][k]*B[n][k] * alpha ----------------
// m97 structure: 128x128 tile, BK=32, 4 waves (2x2), 4x4 16x16x32 MFMA frags/wave,
// global_load_lds width 16, LDS XOR-swizzle (slot ^= (row>>1)&3) applied on BOTH
// the staging global-source side and the ds_read side (linear LDS dest, rule #21).

__device__ __forceinline__ void gload_lds16(const void* g, void* l) {
  __builtin_amdgcn_global_load_lds(
      (const __attribute__((address_space(1))) void*)(uintptr_t)g,
      (__attribute__((address_space(3))) void*)(uintptr_t)l, 16, 0, 0);
}

__global__ __launch_bounds__(256) void gemm_bt_kernel(
    const __hip_bfloat16* __restrict__ A, const __hip_bfloat16* __restrict__ B,
    float* __restrict__ C, const float* __restrict__ scal, int M, int N, int K) {
  __shared__ __align__(16) char AsB[128 * 32 * 2];
  __shared__ __align__(16) char BsB[128 * 32 * 2];

  int nbn = N >> 7;
  int nwg = gridDim.x;
  int bid = blockIdx.x;
  int wg = bid;
  if ((nwg & 7) == 0) {  // XCD-aware swizzle (bijective since nwg % 8 == 0)
    int cpx = nwg >> 3;
    wg = (bid & 7) * cpx + (bid >> 3);
  }
  int bm = wg / nbn, bn = wg % nbn;
  int brow = bm << 7, bcol = bn << 7;

  int tid = threadIdx.x;
  int lane = tid & 63;
  int wave = tid >> 6;
  int wr = wave >> 1, wc = wave & 1;

  // staging: thread covers physical 16B chunks i0, i1 of each 8KB tile.
  // physical (row, slot): byte = row*64 + slot*16; logical kgroup = slot ^ ((row>>1)&3)
  int i0 = tid, i1 = tid + 256;
  int r0 = i0 >> 2, kg0 = (i0 & 3) ^ ((r0 >> 1) & 3);
  int r1 = i1 >> 2, kg1 = (i1 & 3) ^ ((r1 >> 1) & 3);
  const __hip_bfloat16* aSrc0 = A + (size_t)(brow + r0) * K + kg0 * 8;
  const __hip_bfloat16* aSrc1 = A + (size_t)(brow + r1) * K + kg1 * 8;
  const __hip_bfloat16* bSrc0 = B + (size_t)(bcol + r0) * K + kg0 * 8;
  const __hip_bfloat16* bSrc1 = B + (size_t)(bcol + r1) * K + kg1 * 8;
  char* ldsA0 = AsB + i0 * 16; char* ldsA1 = AsB + i1 * 16;
  char* ldsB0 = BsB + i0 * 16; char* ldsB1 = BsB + i1 * 16;

  // fragment read offsets (swizzled): lane reads row (t*16 + lane&15), kgroup = lane>>4
  int aOff[4], bOff[4];
#pragma unroll
  for (int t = 0; t < 4; ++t) {
    int ar = wr * 64 + t * 16 + (lane & 15);
    aOff[t] = ar * 64 + ((((lane >> 4)) ^ ((ar >> 1) & 3)) << 4);
    int br = wc * 64 + t * 16 + (lane & 15);
    bOff[t] = br * 64 + ((((lane >> 4)) ^ ((br >> 1) & 3)) << 4);
  }

  f32x4 acc[4][4] = {};

  for (int kt = 0; kt < K; kt += 32) {
    __syncthreads();  // previous iter's reads done before overwrite
    gload_lds16(aSrc0, ldsA0);
    gload_lds16(aSrc1, ldsA1);
    gload_lds16(bSrc0, ldsB0);
    gload_lds16(bSrc1, ldsB1);
    aSrc0 += 32; aSrc1 += 32; bSrc0 += 32; bSrc1 += 32;
    __syncthreads();  // compiler drains vmcnt(0) here

    bf16x8 af[4], bf[4];
#pragma unroll
    for (int t = 0; t < 4; ++t) {
      af[t] = *(const bf16x8*)(AsB + aOff[t]);
      bf[t] = *(const bf16x8*)(BsB + bOff[t]);
    }
#pragma unroll
    for (int i = 0; i < 4; ++i)
#pragma unroll
      for (int j = 0; j < 4; ++j)
        acc[i][j] = __builtin_amdgcn_mfma_f32_16x16x32_bf16(af[i], bf[j], acc[i][j], 0, 0, 0);
  }

  float gy = 2688.0f / scal[0];
  float gw = 2688.0f / scal[1];
  float alpha = 1.0f / (gy * gw);

  // C/D layout (m89-verified): col = lane&15, row = (lane>>4)*4 + reg
#pragma unroll
  for (int i = 0; i < 4; ++i) {
    int rbase = brow + wr * 64 + i * 16 + ((lane >> 4) << 2);
#pragma unroll
    for (int j = 0; j < 4; ++j) {
      int col = bcol + wc * 64 + j * 16 + (lane & 15);
#pragma unroll
      for (int rg = 0; rg < 4; ++rg) {
        C[(size_t)(rbase + rg) * N + col] = acc[i][j][rg] * alpha;
      }
    }
  }
}

// ---------------- launcher ----------------

extern "C" void kernel_launch(void* const* d_in, const int* in_sizes, int n_in,
                              void* d_out, int out_size, void* d_ws, size_t ws_size,
                              hipStream_t stream) {
  const float* x = (const float*)d_in[0];
  const float* w = (const float*)d_in[1];
  float* out = (float*)d_out;

  // hidden^2 = in_sizes[1] (power of two here)
  int hidden = 1;
  while ((long long)hidden * hidden < (long long)in_sizes[1]) hidden <<= 1;
  int tokens = in_sizes[0] / (2 * hidden);

  char* ws = (char*)d_ws;
  __hip_bfloat16* Aq = (__hip_bfloat16*)ws;                                   // [tokens][hidden] bf16
  __hip_bfloat16* Bq = (__hip_bfloat16*)(ws + (size_t)tokens * hidden * 2);   // [hidden][hidden] bf16
  float* scal = (float*)(ws + (size_t)tokens * hidden * 2 + (size_t)hidden * hidden * 2);

  init_scal_kernel<<<1, 64, 0, stream>>>(scal);
  silu_amax_kernel<<<tokens, 256, 0, stream>>>(x, scal + 0, hidden);
  amax_kernel<<<hidden, 256, 0, stream>>>(w, scal + 1, hidden);
  quant_act_kernel<<<tokens, 256, 0, stream>>>(x, Aq, scal + 0, hidden);
  quant_wt_kernel<<<hidden, 256, 0, stream>>>(w, Bq, scal + 1, hidden);

  int grid = (tokens >> 7) * (hidden >> 7);
  gemm_bt_kernel<<<grid, 256, 0, stream>>>(Aq, Bq, out, scal, tokens, hidden, hidden);
}

// Round 2
// 486.671 us; speedup vs baseline: 1.3128x; 1.3128x over previous
//
#include <hip/hip_runtime.h>
#include <hip/hip_bf16.h>

typedef __attribute__((ext_vector_type(8))) short bf16x8;
typedef __attribute__((ext_vector_type(4))) float f32x4;

// ---------------- numerics (match jnp reference) ----------------

__device__ __forceinline__ float silu_mul_f(float a, float b) {
  float s = 1.0f / (1.0f + expf(-a));
  return (a * s) * b;
}

__device__ __forceinline__ float round_e4m3_f(float a) {  // a >= 0
  if (!(a > 0.0f)) return 0.0f;
  float e = floorf(log2f(a));
  e = fminf(fmaxf(e, -6.0f), 8.0f);
  float s = exp2f(e);
  float q = rintf(a / s * 8.0f) * 0.125f * s;
  return fminf(q, 448.0f);
}

__device__ __forceinline__ float round_e2m1_f(float x) {
  float a = fminf(fabsf(x), 6.0f);
  if (!(a > 0.0f)) return 0.0f;
  float e = fminf(fmaxf(floorf(log2f(a)), 0.0f), 2.0f);
  float step = exp2f(e) * 0.5f;
  float q = rintf(a / step) * step;
  q = fminf(q, 6.0f);
  return (x < 0.0f) ? -q : q;
}

// ---------------- pass 0: zero amax scalars ----------------

__global__ void init_scal_kernel(float* scal) {
  if (threadIdx.x < 2) scal[threadIdx.x] = 0.0f;
}

// ---------------- pass 1: global amax of y = silu_mul(x) ----------------

__global__ void silu_amax_kernel(const float* __restrict__ x, float* __restrict__ amaxp,
                                 int hidden) {
  const float* x1 = x + (size_t)blockIdx.x * (size_t)(2 * hidden);
  const float* x2 = x1 + hidden;
  float m = 0.0f;
  int n4 = hidden >> 2;
  for (int c = threadIdx.x; c < n4; c += blockDim.x) {
    float4 v1 = ((const float4*)x1)[c];
    float4 v2 = ((const float4*)x2)[c];
    m = fmaxf(m, fabsf(silu_mul_f(v1.x, v2.x)));
    m = fmaxf(m, fabsf(silu_mul_f(v1.y, v2.y)));
    m = fmaxf(m, fabsf(silu_mul_f(v1.z, v2.z)));
    m = fmaxf(m, fabsf(silu_mul_f(v1.w, v2.w)));
  }
#pragma unroll
  for (int off = 32; off > 0; off >>= 1) m = fmaxf(m, __shfl_xor(m, off));
  __shared__ float sm[4];
  if ((threadIdx.x & 63) == 0) sm[threadIdx.x >> 6] = m;
  __syncthreads();
  if (threadIdx.x == 0) {
    float mm = fmaxf(fmaxf(sm[0], sm[1]), fmaxf(sm[2], sm[3]));
    atomicMax((unsigned int*)amaxp, __float_as_uint(mm));
  }
}

// ---------------- pass 2: global amax |w| ----------------

__global__ void amax_kernel(const float* __restrict__ p, float* __restrict__ amaxp, int n) {
  const float* row = p + (size_t)blockIdx.x * (size_t)n;
  float m = 0.0f;
  int n4 = n >> 2;
  for (int c = threadIdx.x; c < n4; c += blockDim.x) {
    float4 v = ((const float4*)row)[c];
    m = fmaxf(m, fmaxf(fmaxf(fabsf(v.x), fabsf(v.y)), fmaxf(fabsf(v.z), fabsf(v.w))));
  }
#pragma unroll
  for (int off = 32; off > 0; off >>= 1) m = fmaxf(m, __shfl_xor(m, off));
  __shared__ float sm[4];
  if ((threadIdx.x & 63) == 0) sm[threadIdx.x >> 6] = m;
  __syncthreads();
  if (threadIdx.x == 0) {
    float mm = fmaxf(fmaxf(sm[0], sm[1]), fmaxf(sm[2], sm[3]));
    atomicMax((unsigned int*)amaxp, __float_as_uint(mm));
  }
}

// ---------------- pass 3: quantize activation -> dequant bf16 ----------------

__global__ void quant_act_kernel(const float* __restrict__ x, __hip_bfloat16* __restrict__ A,
                                 const float* __restrict__ amaxp, int hidden) {
  const float gs = 2688.0f / amaxp[0];
  int row = blockIdx.x;
  const float* x1 = x + (size_t)row * (size_t)(2 * hidden);
  const float* x2 = x1 + hidden;
  int nb = hidden >> 4;
  for (int b = threadIdx.x; b < nb; b += blockDim.x) {
    const float* p1 = x1 + b * 16;
    const float* p2 = x2 + b * 16;
    float y[16];
    float bamax = 0.0f;
#pragma unroll
    for (int j = 0; j < 4; ++j) {
      float4 v1 = *(const float4*)(p1 + 4 * j);
      float4 v2 = *(const float4*)(p2 + 4 * j);
      y[4 * j + 0] = silu_mul_f(v1.x, v2.x);
      y[4 * j + 1] = silu_mul_f(v1.y, v2.y);
      y[4 * j + 2] = silu_mul_f(v1.z, v2.z);
      y[4 * j + 3] = silu_mul_f(v1.w, v2.w);
    }
#pragma unroll
    for (int k = 0; k < 16; ++k) bamax = fmaxf(bamax, fabsf(y[k]));
    float bs = round_e4m3_f(bamax / 6.0f * gs);
    float r = gs / (bs > 0.0f ? bs : 1.0f);
    union { bf16x8 v[2]; unsigned short h[16]; } u;
#pragma unroll
    for (int k = 0; k < 16; ++k) {
      float q = round_e2m1_f(y[k] * r);
      float val = q * bs;
      u.h[k] = (unsigned short)(__float_as_uint(val) >> 16);
    }
    bf16x8* dst = (bf16x8*)(A + (size_t)row * (size_t)hidden + (size_t)b * 16);
    dst[0] = u.v[0];
    dst[1] = u.v[1];
  }
}

// ---------------- pass 4: quantize weight -> dequant bf16 ----------------

__global__ void quant_wt_kernel(const float* __restrict__ w, __hip_bfloat16* __restrict__ B,
                                const float* __restrict__ amaxp, int k) {
  const float gs = 2688.0f / amaxp[0];
  int row = blockIdx.x;
  const float* src = w + (size_t)row * (size_t)k;
  int nb = k >> 4;
  for (int b = threadIdx.x; b < nb; b += blockDim.x) {
    const float* p = src + b * 16;
    float y[16];
    float bamax = 0.0f;
#pragma unroll
    for (int j = 0; j < 4; ++j) {
      float4 v = *(const float4*)(p + 4 * j);
      y[4 * j + 0] = v.x; y[4 * j + 1] = v.y; y[4 * j + 2] = v.z; y[4 * j + 3] = v.w;
    }
#pragma unroll
    for (int kk = 0; kk < 16; ++kk) bamax = fmaxf(bamax, fabsf(y[kk]));
    float bs = round_e4m3_f(bamax / 6.0f * gs);
    float r = gs / (bs > 0.0f ? bs : 1.0f);
    union { bf16x8 v[2]; unsigned short h[16]; } u;
#pragma unroll
    for (int kk = 0; kk < 16; ++kk) {
      float q = round_e2m1_f(y[kk] * r);
      float val = q * bs;
      u.h[kk] = (unsigned short)(__float_as_uint(val) >> 16);
    }
    bf16x8* dst = (bf16x8*)(B + (size_t)row * (size_t)k + (size_t)b * 16);
    dst[0] = u.v[0];
    dst[1] = u.v[1];
  }
}

// ---------------- pass 5: 256x256 8-phase bf16 GEMM, out = A @ B^T * alpha ----------------
// 8 waves (2M x 4N), BK=64, 128 KiB LDS double-buffer, counted vmcnt(4) at phases 4/8,
// XOR swizzle slot^=(row&7) on staging-source + frag-read (linear LDS dest).

__device__ __forceinline__ void gload_lds16(const void* g, void* l) {
  __builtin_amdgcn_global_load_lds(
      (const __attribute__((address_space(1))) void*)(uintptr_t)g,
      (__attribute__((address_space(3))) void*)(uintptr_t)l, 16, 0, 0);
}

__device__ __forceinline__ bf16x8 lds_read16(unsigned addr) {
  bf16x8 r;
  asm volatile("ds_read_b128 %0, %1" : "=&v"(r) : "v"(addr));
  return r;
}

__device__ __forceinline__ f32x4 mfma_(bf16x8 a, bf16x8 b, f32x4 c) {
  return __builtin_amdgcn_mfma_f32_16x16x32_bf16(a, b, c, 0, 0, 0);
}

__device__ __forceinline__ void barrier_() {
  asm volatile("" ::: "memory");
  __builtin_amdgcn_s_barrier();
  asm volatile("" ::: "memory");
}

// stage one 128x64 half-tile (16 KiB): 2 x gload_lds16 per thread, linear LDS dest,
// source column permuted by the involution ls = (tid&7) ^ (row&7).
#define STAGE_HALF(gb, rowOff, kt, lofs) do {                                      \
    const __hip_bfloat16* _s = (gb) + (size_t)((rowOff) + r0) * K + (kt) + ls * 8; \
    gload_lds16(_s, ldsT + (lofs));                                                \
    gload_lds16(_s + (size_t)64 * K, ldsT + (lofs) + 8192);                        \
  } while (0)

#define PHASE(cb, mp, LOADB, STAGE_STMT, DO_VMW) do {                              \
    unsigned _ab = aW + (cb) * 32768u + (mp) * 4096u;                              \
    bf16x8 a0k0 = lds_read16(_ab + x0);                                            \
    bf16x8 a0k1 = lds_read16(_ab + x1);                                            \
    bf16x8 a1k0 = lds_read16(_ab + 2048u + x0);                                    \
    bf16x8 a1k1 = lds_read16(_ab + 2048u + x1);                                    \
    if (LOADB) {                                                                   \
      unsigned _bb = bW + (cb) * 32768u;                                           \
      bfr[0][0] = lds_read16(_bb + x0);         bfr[0][1] = lds_read16(_bb + x1);  \
      bfr[1][0] = lds_read16(_bb + 2048u + x0); bfr[1][1] = lds_read16(_bb + 2048u + x1); \
      bfr[2][0] = lds_read16(_bb + 4096u + x0); bfr[2][1] = lds_read16(_bb + 4096u + x1); \
      bfr[3][0] = lds_read16(_bb + 6144u + x0); bfr[3][1] = lds_read16(_bb + 6144u + x1); \
    }                                                                              \
    STAGE_STMT;                                                                    \
    barrier_();                                                                    \
    asm volatile("s_waitcnt lgkmcnt(0)" ::: "memory");                             \
    __builtin_amdgcn_sched_barrier(0);                                             \
    __builtin_amdgcn_s_setprio(1);                                                 \
    acc[2*(mp)+0][0] = mfma_(a0k0, bfr[0][0], acc[2*(mp)+0][0]);                   \
    acc[2*(mp)+0][1] = mfma_(a0k0, bfr[1][0], acc[2*(mp)+0][1]);                   \
    acc[2*(mp)+0][2] = mfma_(a0k0, bfr[2][0], acc[2*(mp)+0][2]);                   \
    acc[2*(mp)+0][3] = mfma_(a0k0, bfr[3][0], acc[2*(mp)+0][3]);                   \
    acc[2*(mp)+1][0] = mfma_(a1k0, bfr[0][0], acc[2*(mp)+1][0]);                   \
    acc[2*(mp)+1][1] = mfma_(a1k0, bfr[1][0], acc[2*(mp)+1][1]);                   \
    acc[2*(mp)+1][2] = mfma_(a1k0, bfr[2][0], acc[2*(mp)+1][2]);                   \
    acc[2*(mp)+1][3] = mfma_(a1k0, bfr[3][0], acc[2*(mp)+1][3]);                   \
    acc[2*(mp)+0][0] = mfma_(a0k1, bfr[0][1], acc[2*(mp)+0][0]);                   \
    acc[2*(mp)+0][1] = mfma_(a0k1, bfr[1][1], acc[2*(mp)+0][1]);                   \
    acc[2*(mp)+0][2] = mfma_(a0k1, bfr[2][1], acc[2*(mp)+0][2]);                   \
    acc[2*(mp)+0][3] = mfma_(a0k1, bfr[3][1], acc[2*(mp)+0][3]);                   \
    acc[2*(mp)+1][0] = mfma_(a1k1, bfr[0][1], acc[2*(mp)+1][0]);                   \
    acc[2*(mp)+1][1] = mfma_(a1k1, bfr[1][1], acc[2*(mp)+1][1]);                   \
    acc[2*(mp)+1][2] = mfma_(a1k1, bfr[2][1], acc[2*(mp)+1][2]);                   \
    acc[2*(mp)+1][3] = mfma_(a1k1, bfr[3][1], acc[2*(mp)+1][3]);                   \
    __builtin_amdgcn_s_setprio(0);                                                 \
    DO_VMW;                                                                        \
    barrier_();                                                                    \
  } while (0)

__global__ __launch_bounds__(512, 2) void gemm_bt_kernel(
    const __hip_bfloat16* __restrict__ A, const __hip_bfloat16* __restrict__ B,
    float* __restrict__ C, const float* __restrict__ scal, int M, int N, int K) {
  // LDS layout: bufA0 @0, bufA1 @32768, bufB0 @65536, bufB1 @98304 (each 256x64 bf16)
  __shared__ __align__(16) char lds[131072];

  const int nbn = N >> 8;
  int nwg = gridDim.x, bid = blockIdx.x, wg = bid;
  if ((nwg & 7) == 0) { int cpx = nwg >> 3; wg = (bid & 7) * cpx + (bid >> 3); }
  const int bm = wg / nbn, bn = wg % nbn;
  const int brow = bm << 8, bcol = bn << 8;

  const int tid = threadIdx.x;
  const int lane = tid & 63;
  const int wave = tid >> 6;
  const int wm = wave >> 2, wn = wave & 3;

  // staging geometry: chunk i = tid + pass*512; row = i>>3, phys slot = i&7,
  // logical slot = (i&7) ^ (row&7)  (same for both passes since rows differ by 64)
  const int r0 = tid >> 3;
  const int ls = (tid & 7) ^ (r0 & 7);
  const __hip_bfloat16* Abase = A + (size_t)brow * K;
  const __hip_bfloat16* Bbase = B + (size_t)bcol * K;
  char* ldsT = lds + tid * 16;

  // fragment-read addressing (swizzled): row R = wbase + m*16 + (lane&15),
  // logical slot = ks*4 + (lane>>4), phys slot = logical ^ (R&7) = logical ^ (lane&7)
  const unsigned ldsBase = (unsigned)(uintptr_t)lds;
  const unsigned q = (unsigned)(lane >> 4);
  const unsigned fbase = (unsigned)((lane & 15) * 128);
  const unsigned x0 = ((q + 0u) ^ (unsigned)(lane & 7)) << 4;
  const unsigned x1 = ((q + 4u) ^ (unsigned)(lane & 7)) << 4;
  const unsigned aW = ldsBase + (unsigned)(wm * 16384) + fbase;
  const unsigned bW = ldsBase + 65536u + (unsigned)(wn * 8192) + fbase;

  f32x4 acc[8][4] = {};
  bf16x8 bfr[4][2];

  // prologue: buf0.A(kt0), buf0.B(kt0), buf1.B(kt0+64); buf1.A staged in P1/P2
  STAGE_HALF(Abase, 0,   0, 0);
  STAGE_HALF(Abase, 128, 0, 16384);
  STAGE_HALF(Bbase, 0,   0, 65536);
  STAGE_HALF(Bbase, 128, 0, 65536 + 16384);
  STAGE_HALF(Bbase, 0,   64, 65536 + 32768);
  STAGE_HALF(Bbase, 128, 64, 65536 + 32768 + 16384);
  asm volatile("s_waitcnt vmcnt(4)" ::: "memory");  // buf0 complete; buf1.B in flight
  barrier_();

  const int niter = K >> 7;  // 2 K-tiles (BK=64) per iteration
  for (int it = 0; it < niter; ++it) {
    int kt0 = it << 7;
    int kp2 = kt0 + 128; if (kp2 >= K) kp2 = 0;  // clamped dead prefetch at tail
    int kp3 = kt0 + 192; if (kp3 >= K) kp3 = 0;
    // phases 1-4: consume buf0 (K-tile kt0); prefetch buf1.A(kt0+64), buf0.B(kt0+128)
    PHASE(0, 0, 1, STAGE_HALF(Abase, 0,   kt0 + 64, 32768), );
    PHASE(0, 1, 0, STAGE_HALF(Abase, 128, kt0 + 64, 32768 + 16384), );
    PHASE(0, 2, 0, STAGE_HALF(Bbase, 0,   kp2, 65536), );
    PHASE(0, 3, 0, STAGE_HALF(Bbase, 128, kp2, 65536 + 16384),
          asm volatile("s_waitcnt vmcnt(4)" ::: "memory"));
    // phases 5-8: consume buf1 (K-tile kt0+64); prefetch buf0.A(kt0+128), buf1.B(kt0+192)
    PHASE(1, 0, 1, STAGE_HALF(Abase, 0,   kp2, 0), );
    PHASE(1, 1, 0, STAGE_HALF(Abase, 128, kp2, 16384), );
    PHASE(1, 2, 0, STAGE_HALF(Bbase, 0,   kp3, 65536 + 32768), );
    PHASE(1, 3, 0, STAGE_HALF(Bbase, 128, kp3, 65536 + 32768 + 16384),
          asm volatile("s_waitcnt vmcnt(4)" ::: "memory"));
  }
  asm volatile("s_waitcnt vmcnt(0)" ::: "memory");  // drain before endpgm / LDS reuse

  float gy = 2688.0f / scal[0];
  float gw = 2688.0f / scal[1];
  float alpha = 1.0f / (gy * gw);

  // C/D layout: col = lane&15, row = (lane>>4)*4 + reg
#pragma unroll
  for (int m = 0; m < 8; ++m) {
    int rbase = brow + wm * 128 + m * 16 + ((lane >> 4) << 2);
#pragma unroll
    for (int n = 0; n < 4; ++n) {
      int col = bcol + wn * 64 + n * 16 + (lane & 15);
#pragma unroll
      for (int rg = 0; rg < 4; ++rg) {
        C[(size_t)(rbase + rg) * N + col] = acc[m][n][rg] * alpha;
      }
    }
  }
}

// ---------------- launcher ----------------

extern "C" void kernel_launch(void* const* d_in, const int* in_sizes, int n_in,
                              void* d_out, int out_size, void* d_ws, size_t ws_size,
                              hipStream_t stream) {
  const float* x = (const float*)d_in[0];
  const float* w = (const float*)d_in[1];
  float* out = (float*)d_out;

  int hidden = 1;
  while ((long long)hidden * hidden < (long long)in_sizes[1]) hidden <<= 1;
  int tokens = in_sizes[0] / (2 * hidden);

  char* ws = (char*)d_ws;
  __hip_bfloat16* Aq = (__hip_bfloat16*)ws;
  __hip_bfloat16* Bq = (__hip_bfloat16*)(ws + (size_t)tokens * hidden * 2);
  float* scal = (float*)(ws + (size_t)tokens * hidden * 2 + (size_t)hidden * hidden * 2);

  init_scal_kernel<<<1, 64, 0, stream>>>(scal);
  silu_amax_kernel<<<tokens, 256, 0, stream>>>(x, scal + 0, hidden);
  amax_kernel<<<hidden, 256, 0, stream>>>(w, scal + 1, hidden);
  quant_act_kernel<<<tokens, 256, 0, stream>>>(x, Aq, scal + 0, hidden);
  quant_wt_kernel<<<hidden, 256, 0, stream>>>(w, Bq, scal + 1, hidden);

  int grid = (tokens >> 8) * (hidden >> 8);  // 256x256 tiles
  gemm_bt_kernel<<<grid, 512, 0, stream>>>(Aq, Bq, out, scal, tokens, hidden, hidden);
}

// Round 3
// 486.628 us; speedup vs baseline: 1.3129x; 1.0001x over previous
//
#include <hip/hip_runtime.h>
#include <hip/hip_bf16.h>

typedef __attribute__((ext_vector_type(8))) short bf16x8;
typedef __attribute__((ext_vector_type(4))) float f32x4;

// ---------------- numerics (match jnp reference) ----------------

__device__ __forceinline__ float silu_mul_f(float a, float b) {
  float s = 1.0f / (1.0f + expf(-a));
  return (a * s) * b;
}

__device__ __forceinline__ float round_e4m3_f(float a) {  // a >= 0
  if (!(a > 0.0f)) return 0.0f;
  float e = floorf(log2f(a));
  e = fminf(fmaxf(e, -6.0f), 8.0f);
  float s = exp2f(e);
  float q = rintf(a / s * 8.0f) * 0.125f * s;
  return fminf(q, 448.0f);
}

__device__ __forceinline__ float round_e2m1_f(float x) {
  float a = fminf(fabsf(x), 6.0f);
  if (!(a > 0.0f)) return 0.0f;
  float e = fminf(fmaxf(floorf(log2f(a)), 0.0f), 2.0f);
  float step = exp2f(e) * 0.5f;
  float q = rintf(a / step) * step;
  q = fminf(q, 6.0f);
  return (x < 0.0f) ? -q : q;
}

__global__ void init_scal_kernel(float* scal) {
  if (threadIdx.x < 2) scal[threadIdx.x] = 0.0f;
}

// ---------------- fused pass 1: amax of silu_mul rows AND |w| rows ----------------

__global__ void fused_amax_kernel(const float* __restrict__ x, const float* __restrict__ w,
                                  float* __restrict__ scal, int tokens, int hidden) {
  float m = 0.0f;
  if ((int)blockIdx.x < tokens) {
    const float* x1 = x + (size_t)blockIdx.x * (size_t)(2 * hidden);
    const float* x2 = x1 + hidden;
    int n4 = hidden >> 2;
    for (int c = threadIdx.x; c < n4; c += blockDim.x) {
      float4 v1 = ((const float4*)x1)[c];
      float4 v2 = ((const float4*)x2)[c];
      m = fmaxf(m, fabsf(silu_mul_f(v1.x, v2.x)));
      m = fmaxf(m, fabsf(silu_mul_f(v1.y, v2.y)));
      m = fmaxf(m, fabsf(silu_mul_f(v1.z, v2.z)));
      m = fmaxf(m, fabsf(silu_mul_f(v1.w, v2.w)));
    }
  } else {
    const float* row = w + (size_t)(blockIdx.x - tokens) * (size_t)hidden;
    int n4 = hidden >> 2;
    for (int c = threadIdx.x; c < n4; c += blockDim.x) {
      float4 v = ((const float4*)row)[c];
      m = fmaxf(m, fmaxf(fmaxf(fabsf(v.x), fabsf(v.y)), fmaxf(fabsf(v.z), fabsf(v.w))));
    }
  }
#pragma unroll
  for (int off = 32; off > 0; off >>= 1) m = fmaxf(m, __shfl_xor(m, off));
  __shared__ float sm[4];
  if ((threadIdx.x & 63) == 0) sm[threadIdx.x >> 6] = m;
  __syncthreads();
  if (threadIdx.x == 0) {
    float mm = fmaxf(fmaxf(sm[0], sm[1]), fmaxf(sm[2], sm[3]));
    unsigned int* dst = (unsigned int*)(scal + ((int)blockIdx.x < tokens ? 0 : 1));
    atomicMax(dst, __float_as_uint(mm));
  }
}

// ---------------- fused pass 2: quantize act AND weight -> dequant bf16 ----------------

__device__ __forceinline__ void quant_block16(const float* y, float gs, __hip_bfloat16* dst) {
  float bamax = 0.0f;
#pragma unroll
  for (int k = 0; k < 16; ++k) bamax = fmaxf(bamax, fabsf(y[k]));
  float bs = round_e4m3_f(bamax / 6.0f * gs);
  float r = gs / (bs > 0.0f ? bs : 1.0f);
  union { bf16x8 v[2]; unsigned short h[16]; } u;
#pragma unroll
  for (int k = 0; k < 16; ++k) {
    float q = round_e2m1_f(y[k] * r);
    float val = q * bs;  // <= 6 significant bits -> exact in bf16
    u.h[k] = (unsigned short)(__float_as_uint(val) >> 16);
  }
  ((bf16x8*)dst)[0] = u.v[0];
  ((bf16x8*)dst)[1] = u.v[1];
}

__global__ void fused_quant_kernel(const float* __restrict__ x, const float* __restrict__ w,
                                   __hip_bfloat16* __restrict__ A, __hip_bfloat16* __restrict__ B,
                                   const float* __restrict__ scal, int tokens, int hidden) {
  int nb = hidden >> 4;
  if ((int)blockIdx.x < tokens) {
    const float gs = 2688.0f / scal[0];
    int row = blockIdx.x;
    const float* x1 = x + (size_t)row * (size_t)(2 * hidden);
    const float* x2 = x1 + hidden;
    for (int b = threadIdx.x; b < nb; b += blockDim.x) {
      const float* p1 = x1 + b * 16;
      const float* p2 = x2 + b * 16;
      float y[16];
#pragma unroll
      for (int j = 0; j < 4; ++j) {
        float4 v1 = *(const float4*)(p1 + 4 * j);
        float4 v2 = *(const float4*)(p2 + 4 * j);
        y[4 * j + 0] = silu_mul_f(v1.x, v2.x);
        y[4 * j + 1] = silu_mul_f(v1.y, v2.y);
        y[4 * j + 2] = silu_mul_f(v1.z, v2.z);
        y[4 * j + 3] = silu_mul_f(v1.w, v2.w);
      }
      quant_block16(y, gs, A + (size_t)row * (size_t)hidden + (size_t)b * 16);
    }
  } else {
    const float gs = 2688.0f / scal[1];
    int row = blockIdx.x - tokens;
    const float* src = w + (size_t)row * (size_t)hidden;
    for (int b = threadIdx.x; b < nb; b += blockDim.x) {
      const float* p = src + b * 16;
      float y[16];
#pragma unroll
      for (int j = 0; j < 4; ++j) {
        float4 v = *(const float4*)(p + 4 * j);
        y[4 * j + 0] = v.x; y[4 * j + 1] = v.y; y[4 * j + 2] = v.z; y[4 * j + 3] = v.w;
      }
      quant_block16(y, gs, B + (size_t)row * (size_t)hidden + (size_t)b * 16);
    }
  }
}

// ---------------- pass 3: 256x256 bf16 GEMM, cluster-pipelined, out = A@B^T * alpha -------
// 8 waves (2M x 4N), BK=64, 2x64KiB LDS double-buffer. Per K-tile: 8 clusters of 8 MFMA
// (k-split), ONE barrier + ONE vmcnt(0), counted lgkm waits, reads pipelined 2 clusters
// ahead; next-tile entry reads issued during clusters 6-7 (hidden under MFMA).
// XOR swizzle slot^=(row&7) on staging-source + frag-read (linear LDS dest, rule #21).

__device__ __forceinline__ void gload_lds16(const void* g, void* l) {
  __builtin_amdgcn_global_load_lds(
      (const __attribute__((address_space(1))) void*)(uintptr_t)g,
      (__attribute__((address_space(3))) void*)(uintptr_t)l, 16, 0, 0);
}

__device__ __forceinline__ bf16x8 lds_read16(unsigned addr) {
  bf16x8 r;
  asm volatile("ds_read_b128 %0, %1" : "=&v"(r) : "v"(addr));
  return r;
}

__device__ __forceinline__ f32x4 mfma_(bf16x8 a, bf16x8 b, f32x4 c) {
  return __builtin_amdgcn_mfma_f32_16x16x32_bf16(a, b, c, 0, 0, 0);
}

#define SP1 __builtin_amdgcn_s_setprio(1)
#define SP0 __builtin_amdgcn_s_setprio(0)
#define SCHEDB __builtin_amdgcn_sched_barrier(0)
#define WAITL(n) do { asm volatile("s_waitcnt lgkmcnt(" #n ")" ::: "memory"); SCHEDB; } while (0)

#define DSA(sl, vAk, IMM) do {                       \
    a_s[sl][0] = lds_read16((vAk) + (IMM));          \
    a_s[sl][1] = lds_read16((vAk) + (IMM) + 2048u);  \
  } while (0)

#define DSB(kk, vBk, IMM) do {                       \
    b_s[kk][0] = lds_read16((vBk) + (IMM));          \
    b_s[kk][1] = lds_read16((vBk) + (IMM) + 2048u);  \
    b_s[kk][2] = lds_read16((vBk) + (IMM) + 4096u);  \
    b_s[kk][3] = lds_read16((vBk) + (IMM) + 6144u);  \
  } while (0)

#define MFMA8(mp, kk) do {                                             \
    acc[2*(mp)+0][0] = mfma_(a_s[mp][0], b_s[kk][0], acc[2*(mp)+0][0]); \
    acc[2*(mp)+1][0] = mfma_(a_s[mp][1], b_s[kk][0], acc[2*(mp)+1][0]); \
    acc[2*(mp)+0][1] = mfma_(a_s[mp][0], b_s[kk][1], acc[2*(mp)+0][1]); \
    acc[2*(mp)+1][1] = mfma_(a_s[mp][1], b_s[kk][1], acc[2*(mp)+1][1]); \
    acc[2*(mp)+0][2] = mfma_(a_s[mp][0], b_s[kk][2], acc[2*(mp)+0][2]); \
    acc[2*(mp)+1][2] = mfma_(a_s[mp][1], b_s[kk][2], acc[2*(mp)+1][2]); \
    acc[2*(mp)+0][3] = mfma_(a_s[mp][0], b_s[kk][3], acc[2*(mp)+0][3]); \
    acc[2*(mp)+1][3] = mfma_(a_s[mp][1], b_s[kk][3], acc[2*(mp)+1][3]); \
  } while (0)

// stage full next tile (A 256x64 + B 256x64) into buffer at LDS offset BON; sk = col byte off
#define STAGE8(BON, SK) do {                                             \
    gload_lds16(pA0 + (SK), ldsT + (BON));                               \
    gload_lds16(pA0 + (SK) + rowBig, ldsT + (BON) + 8192);               \
    gload_lds16(pA128 + (SK), ldsT + (BON) + 16384);                     \
    gload_lds16(pA128 + (SK) + rowBig, ldsT + (BON) + 16384 + 8192);     \
    gload_lds16(pB0 + (SK), ldsT + 65536 + (BON));                       \
    gload_lds16(pB0 + (SK) + rowBig, ldsT + 65536 + (BON) + 8192);       \
    gload_lds16(pB128 + (SK), ldsT + 65536 + (BON) + 16384);             \
    gload_lds16(pB128 + (SK) + rowBig, ldsT + 65536 + (BON) + 16384 + 8192); \
  } while (0)

// one K-tile: consume buffer CB, stage next into CB^1, prefetch next-tile entry frags
#define TILE(CB) do {                                                    \
    const unsigned bo  = (CB) * 32768u;                                  \
    const unsigned bon = ((CB) ^ 1) * 32768u;                            \
    STAGE8(bon, sk);                                                     \
    sk = (sk + 128u) & skMask;                                           \
    WAITL(2); DSA(2, vA0, bo + 8192u);                                   \
    SP1; MFMA8(0, 0); SP0;                                               \
    WAITL(2); DSA(3, vA0, bo + 12288u);                                  \
    SP1; MFMA8(1, 0); SP0;                                               \
    WAITL(2); DSB(1, vB1, bo); DSA(0, vA1, bo);                          \
    SP1; MFMA8(2, 0); SP0;                                               \
    WAITL(6); DSA(1, vA1, bo + 4096u);                                   \
    SP1; MFMA8(3, 0); SP0;                                               \
    WAITL(2); DSA(2, vA1, bo + 8192u); DSA(3, vA1, bo + 12288u);         \
    SP1; MFMA8(0, 1); SP0;                                               \
    WAITL(4);                                                            \
    SP1; MFMA8(1, 1); SP0;                                               \
    asm volatile("s_waitcnt lgkmcnt(0)" ::: "memory");                   \
    asm volatile("s_waitcnt vmcnt(0)" ::: "memory");                     \
    __builtin_amdgcn_s_barrier();                                        \
    SCHEDB;                                                              \
    DSB(0, vB0, bon); DSA(0, vA0, bon);                                  \
    SP1; MFMA8(2, 1); SP0;                                               \
    DSA(1, vA0, bon + 4096u);                                            \
    SP1; MFMA8(3, 1); SP0;                                               \
  } while (0)

__global__ __launch_bounds__(512, 2) void gemm_bt_kernel(
    const __hip_bfloat16* __restrict__ A, const __hip_bfloat16* __restrict__ B,
    float* __restrict__ C, const float* __restrict__ scal, int M, int N, int K) {
  // LDS: A buf0 @0, A buf1 @32768, B buf0 @65536, B buf1 @98304 (each 256x64 bf16)
  __shared__ __align__(16) char lds[131072];

  const int nbn = N >> 8;
  int nwg = gridDim.x, bid = blockIdx.x, wg = bid;
  if ((nwg & 7) == 0) { int cpx = nwg >> 3; wg = (bid & 7) * cpx + (bid >> 3); }
  const int bm = wg / nbn, bn = wg % nbn;
  const int brow = bm << 8, bcol = bn << 8;

  const int tid = threadIdx.x;
  const int lane = tid & 63;
  const int wave = tid >> 6;
  const int wm = wave >> 2, wn = wave & 3;

  // staging geometry: thread covers chunk tid (rows 0-63) and tid+512 (rows 64-127)
  // of each 128-row half; source column permuted by involution ls = (tid&7)^(row&7)
  const int r0 = tid >> 3;
  const int ls = (tid & 7) ^ (r0 & 7);
  const char* pA0   = (const char*)(A + (size_t)(brow + r0) * K + ls * 8);
  const char* pA128 = (const char*)(A + (size_t)(brow + 128 + r0) * K + ls * 8);
  const char* pB0   = (const char*)(B + (size_t)(bcol + r0) * K + ls * 8);
  const char* pB128 = (const char*)(B + (size_t)(bcol + 128 + r0) * K + ls * 8);
  const size_t rowBig = (size_t)64 * K * 2;   // +64 rows in bytes
  char* ldsT = lds + tid * 16;

  // fragment-read addressing: row R = wbase + 16m + (lane&15), phys slot = logical^(lane&7)
  const unsigned ldsBase = (unsigned)(uintptr_t)lds;
  const unsigned q = (unsigned)(lane >> 4);
  const unsigned fbase = (unsigned)((lane & 15) * 128);
  const unsigned x0 = ((q + 0u) ^ (unsigned)(lane & 7)) << 4;
  const unsigned x1 = ((q + 4u) ^ (unsigned)(lane & 7)) << 4;
  const unsigned vA0 = ldsBase + (unsigned)(wm * 16384) + fbase + x0;
  const unsigned vA1 = ldsBase + (unsigned)(wm * 16384) + fbase + x1;
  const unsigned vB0 = ldsBase + 65536u + (unsigned)(wn * 8192) + fbase + x0;
  const unsigned vB1 = ldsBase + 65536u + (unsigned)(wn * 8192) + fbase + x1;

  f32x4 acc[8][4] = {};
  bf16x8 a_s[4][2];
  bf16x8 b_s[2][4];

  const unsigned skMask = (unsigned)(K * 2 - 1);  // K*2 is pow2 here (K=4096)
  unsigned sk = 128u;                             // tile 0 stages tile 1

  // prologue: stage tile 0 -> buf0, publish, prefetch entry frags for tile 0
  STAGE8(0, 0);
  asm volatile("s_waitcnt vmcnt(0)" ::: "memory");
  __builtin_amdgcn_s_barrier();
  SCHEDB;
  DSB(0, vB0, 0u); DSA(0, vA0, 0u); DSA(1, vA0, 4096u);

  const int niter = K >> 7;  // 2 K-tiles per iteration
  for (int it = 0; it < niter; ++it) {
    TILE(0);
    TILE(1);
  }
  asm volatile("s_waitcnt lgkmcnt(0)" ::: "memory");
  asm volatile("s_waitcnt vmcnt(0)" ::: "memory");

  float gy = 2688.0f / scal[0];
  float gw = 2688.0f / scal[1];
  float alpha = 1.0f / (gy * gw);

  // C/D layout: col = lane&15, row = (lane>>4)*4 + reg
#pragma unroll
  for (int m = 0; m < 8; ++m) {
    int rbase = brow + wm * 128 + m * 16 + ((lane >> 4) << 2);
#pragma unroll
    for (int n = 0; n < 4; ++n) {
      int col = bcol + wn * 64 + n * 16 + (lane & 15);
#pragma unroll
      for (int rg = 0; rg < 4; ++rg) {
        C[(size_t)(rbase + rg) * N + col] = acc[m][n][rg] * alpha;
      }
    }
  }
}

// ---------------- launcher ----------------

extern "C" void kernel_launch(void* const* d_in, const int* in_sizes, int n_in,
                              void* d_out, int out_size, void* d_ws, size_t ws_size,
                              hipStream_t stream) {
  const float* x = (const float*)d_in[0];
  const float* w = (const float*)d_in[1];
  float* out = (float*)d_out;

  int hidden = 1;
  while ((long long)hidden * hidden < (long long)in_sizes[1]) hidden <<= 1;
  int tokens = in_sizes[0] / (2 * hidden);

  char* ws = (char*)d_ws;
  __hip_bfloat16* Aq = (__hip_bfloat16*)ws;
  __hip_bfloat16* Bq = (__hip_bfloat16*)(ws + (size_t)tokens * hidden * 2);
  float* scal = (float*)(ws + (size_t)tokens * hidden * 2 + (size_t)hidden * hidden * 2);

  init_scal_kernel<<<1, 64, 0, stream>>>(scal);
  fused_amax_kernel<<<tokens + hidden, 256, 0, stream>>>(x, w, scal, tokens, hidden);
  fused_quant_kernel<<<tokens + hidden, 256, 0, stream>>>(x, w, Aq, Bq, scal, tokens, hidden);

  int grid = (tokens >> 8) * (hidden >> 8);  // 256x256 tiles
  gemm_bt_kernel<<<grid, 512, 0, stream>>>(Aq, Bq, out, scal, tokens, hidden, hidden);
}

// Round 4
// 453.625 us; speedup vs baseline: 1.4085x; 1.0728x over previous
//
#include <hip/hip_runtime.h>
#include <hip/hip_bf16.h>

typedef __attribute__((ext_vector_type(8))) short bf16x8;
typedef __attribute__((ext_vector_type(4))) float f32x4;

// ---------------- numerics (match jnp reference) ----------------

__device__ __forceinline__ float silu_mul_f(float a, float b) {
  float s = 1.0f / (1.0f + expf(-a));
  return (a * s) * b;
}

// floor(log2(a)) for a>0 via exponent bits (subnormals -> -127, clamped by callers)
__device__ __forceinline__ int flog2(float a) {
  return (int)((__float_as_uint(a) >> 23) & 255u) - 127;
}
__device__ __forceinline__ float exp2i(int e) {  // exact 2^e, e in [-126,127]
  return __uint_as_float((unsigned)(e + 127) << 23);
}

__device__ __forceinline__ float round_e4m3_f(float a) {  // a >= 0
  if (!(a > 0.0f)) return 0.0f;
  int e = flog2(a);
  e = e < -6 ? -6 : (e > 8 ? 8 : e);
  float q = rintf(a * exp2i(3 - e)) * exp2i(e - 3);  // a/2^e*8 exact; rint = half-even
  return fminf(q, 448.0f);
}

__device__ __forceinline__ float round_e2m1_f(float x) {
  float a = fminf(fabsf(x), 6.0f);
  if (!(a > 0.0f)) return 0.0f;
  int e = flog2(a);
  e = e < 0 ? 0 : (e > 2 ? 2 : e);
  float q = rintf(a * exp2i(1 - e)) * exp2i(e - 1);  // step = 2^(e-1)
  q = fminf(q, 6.0f);
  return (x < 0.0f) ? -q : q;
}

__global__ void init_scal_kernel(float* scal) {
  if (threadIdx.x < 2) scal[threadIdx.x] = 0.0f;
}

// ---------------- fused pass 1: amax of silu_mul rows AND |w| rows ----------------

__global__ void fused_amax_kernel(const float* __restrict__ x, const float* __restrict__ w,
                                  float* __restrict__ scal, int tokens, int hidden) {
  float m = 0.0f;
  if ((int)blockIdx.x < tokens) {
    const float* x1 = x + (size_t)blockIdx.x * (size_t)(2 * hidden);
    const float* x2 = x1 + hidden;
    int n4 = hidden >> 2;
    for (int c = threadIdx.x; c < n4; c += blockDim.x) {
      float4 v1 = ((const float4*)x1)[c];
      float4 v2 = ((const float4*)x2)[c];
      m = fmaxf(m, fabsf(silu_mul_f(v1.x, v2.x)));
      m = fmaxf(m, fabsf(silu_mul_f(v1.y, v2.y)));
      m = fmaxf(m, fabsf(silu_mul_f(v1.z, v2.z)));
      m = fmaxf(m, fabsf(silu_mul_f(v1.w, v2.w)));
    }
  } else {
    const float* row = w + (size_t)(blockIdx.x - tokens) * (size_t)hidden;
    int n4 = hidden >> 2;
    for (int c = threadIdx.x; c < n4; c += blockDim.x) {
      float4 v = ((const float4*)row)[c];
      m = fmaxf(m, fmaxf(fmaxf(fabsf(v.x), fabsf(v.y)), fmaxf(fabsf(v.z), fabsf(v.w))));
    }
  }
#pragma unroll
  for (int off = 32; off > 0; off >>= 1) m = fmaxf(m, __shfl_xor(m, off));
  __shared__ float sm[4];
  if ((threadIdx.x & 63) == 0) sm[threadIdx.x >> 6] = m;
  __syncthreads();
  if (threadIdx.x == 0) {
    float mm = fmaxf(fmaxf(sm[0], sm[1]), fmaxf(sm[2], sm[3]));
    unsigned int* dst = (unsigned int*)(scal + ((int)blockIdx.x < tokens ? 0 : 1));
    atomicMax(dst, __float_as_uint(mm));
  }
}

// ---------------- fused pass 2: quantize act AND weight -> dequant bf16 ----------------

__device__ __forceinline__ void quant_block16(const float* y, float gs, __hip_bfloat16* dst) {
  float bamax = 0.0f;
#pragma unroll
  for (int k = 0; k < 16; ++k) bamax = fmaxf(bamax, fabsf(y[k]));
  float bs = round_e4m3_f(bamax * (1.0f / 6.0f) * 6.0f == 0.0f ? 0.0f : bamax / 6.0f * gs);
  float r = gs / (bs > 0.0f ? bs : 1.0f);
  union { bf16x8 v[2]; unsigned short h[16]; } u;
#pragma unroll
  for (int k = 0; k < 16; ++k) {
    float q = round_e2m1_f(y[k] * r);
    float val = q * bs;  // <= 6 significant bits -> exact in bf16
    u.h[k] = (unsigned short)(__float_as_uint(val) >> 16);
  }
  ((bf16x8*)dst)[0] = u.v[0];
  ((bf16x8*)dst)[1] = u.v[1];
}

__global__ void fused_quant_kernel(const float* __restrict__ x, const float* __restrict__ w,
                                   __hip_bfloat16* __restrict__ A, __hip_bfloat16* __restrict__ B,
                                   const float* __restrict__ scal, int tokens, int hidden) {
  int nb = hidden >> 4;
  if ((int)blockIdx.x < tokens) {
    const float gs = 2688.0f / scal[0];
    int row = blockIdx.x;
    const float* x1 = x + (size_t)row * (size_t)(2 * hidden);
    const float* x2 = x1 + hidden;
    for (int b = threadIdx.x; b < nb; b += blockDim.x) {
      const float* p1 = x1 + b * 16;
      const float* p2 = x2 + b * 16;
      float y[16];
#pragma unroll
      for (int j = 0; j < 4; ++j) {
        float4 v1 = *(const float4*)(p1 + 4 * j);
        float4 v2 = *(const float4*)(p2 + 4 * j);
        y[4 * j + 0] = silu_mul_f(v1.x, v2.x);
        y[4 * j + 1] = silu_mul_f(v1.y, v2.y);
        y[4 * j + 2] = silu_mul_f(v1.z, v2.z);
        y[4 * j + 3] = silu_mul_f(v1.w, v2.w);
      }
      quant_block16(y, gs, A + (size_t)row * (size_t)hidden + (size_t)b * 16);
    }
  } else {
    const float gs = 2688.0f / scal[1];
    int row = blockIdx.x - tokens;
    const float* src = w + (size_t)row * (size_t)hidden;
    for (int b = threadIdx.x; b < nb; b += blockDim.x) {
      const float* p = src + b * 16;
      float y[16];
#pragma unroll
      for (int j = 0; j < 4; ++j) {
        float4 v = *(const float4*)(p + 4 * j);
        y[4 * j + 0] = v.x; y[4 * j + 1] = v.y; y[4 * j + 2] = v.z; y[4 * j + 3] = v.w;
      }
      quant_block16(y, gs, B + (size_t)row * (size_t)hidden + (size_t)b * 16);
    }
  }
}

// ---------------- pass 3: 256x256 bf16 GEMM, never-drain pipelined, out = A@B^T*alpha ----
// 8 waves (2M x 4N). BK=64 split in two K-halves of 32; LDS regions (16KB each):
// A[parity][khalf] @ parity*32768 + khalf*16384, B same +65536. 4 phases/tile:
//   P1: k0 x m0-3 | P2: k0 x m4-7 | P3: k1 x m0-3 | P4: k1 x m4-7
// ds-reads pipelined 1 phase ahead (counted lgkmcnt), 1 sub-tile staged per phase,
// vmcnt(4) gates at P2/P4 only -> global_load_lds NEVER drains to 0 in the loop.
// Sub-tile layout: addr = row*64 + phys*16, phys = kchunk ^ ((row>>1)&3)  (2-way banks,
// free per m136); staging sources pre-permuted by the same involution (rule #21).

__device__ __forceinline__ void gload_lds16(const void* g, void* l) {
  __builtin_amdgcn_global_load_lds(
      (const __attribute__((address_space(1))) void*)(uintptr_t)g,
      (__attribute__((address_space(3))) void*)(uintptr_t)l, 16, 0, 0);
}

template <unsigned IMM>
__device__ __forceinline__ bf16x8 lds_read16o(unsigned addr) {
  bf16x8 r;
  asm volatile("ds_read_b128 %0, %1 offset:%c2" : "=&v"(r) : "v"(addr), "i"(IMM));
  return r;
}

__device__ __forceinline__ f32x4 mfma_(bf16x8 a, bf16x8 b, f32x4 c) {
  return __builtin_amdgcn_mfma_f32_16x16x32_bf16(a, b, c, 0, 0, 0);
}

#define SP1 __builtin_amdgcn_s_setprio(1)
#define SP0 __builtin_amdgcn_s_setprio(0)
#define SCHEDB __builtin_amdgcn_sched_barrier(0)
#define WAITL(n) do { asm volatile("s_waitcnt lgkmcnt(" #n ")" ::: "memory"); SCHEDB; } while (0)
#define VMW4 do { asm volatile("s_waitcnt vmcnt(4)" ::: "memory"); } while (0)

#define STAGEA(PP, HH, KSB) do {                                        \
    const char* _s = pa + (KSB) + (HH) * 64;                            \
    gload_lds16(_s, ldsStA + (PP) * 32768 + (HH) * 16384);              \
    gload_lds16(_s + rowBig, ldsStA + (PP) * 32768 + (HH) * 16384 + 8192); } while (0)

#define STAGEB(PP, HH, KSB) do {                                        \
    const char* _s = pb + (KSB) + (HH) * 64;                            \
    gload_lds16(_s, ldsStB + (PP) * 32768 + (HH) * 16384);              \
    gload_lds16(_s + rowBig, ldsStB + (PP) * 32768 + (HH) * 16384 + 8192); } while (0)

#define RDA4(DST, PP, HH, MB) do {                                              \
    DST[0] = lds_read16o<(PP)*32768u + (HH)*16384u + ((MB)+0)*1024u>(vA);       \
    DST[1] = lds_read16o<(PP)*32768u + (HH)*16384u + ((MB)+1)*1024u>(vA);       \
    DST[2] = lds_read16o<(PP)*32768u + (HH)*16384u + ((MB)+2)*1024u>(vA);       \
    DST[3] = lds_read16o<(PP)*32768u + (HH)*16384u + ((MB)+3)*1024u>(vA); } while (0)

#define RDB4(DST, PP, HH) do {                                                  \
    DST[0] = lds_read16o<(PP)*32768u + (HH)*16384u + 0u>(vB);                   \
    DST[1] = lds_read16o<(PP)*32768u + (HH)*16384u + 1024u>(vB);                \
    DST[2] = lds_read16o<(PP)*32768u + (HH)*16384u + 2048u>(vB);                \
    DST[3] = lds_read16o<(PP)*32768u + (HH)*16384u + 3072u>(vB); } while (0)

#define MFMA16(AF, BF, MB) do {                                                  \
    acc[(MB)+0][0] = mfma_(AF[0], BF[0], acc[(MB)+0][0]);                        \
    acc[(MB)+1][0] = mfma_(AF[1], BF[0], acc[(MB)+1][0]);                        \
    acc[(MB)+2][0] = mfma_(AF[2], BF[0], acc[(MB)+2][0]);                        \
    acc[(MB)+3][0] = mfma_(AF[3], BF[0], acc[(MB)+3][0]);                        \
    acc[(MB)+0][1] = mfma_(AF[0], BF[1], acc[(MB)+0][1]);                        \
    acc[(MB)+1][1] = mfma_(AF[1], BF[1], acc[(MB)+1][1]);                        \
    acc[(MB)+2][1] = mfma_(AF[2], BF[1], acc[(MB)+2][1]);                        \
    acc[(MB)+3][1] = mfma_(AF[3], BF[1], acc[(MB)+3][1]);                        \
    acc[(MB)+0][2] = mfma_(AF[0], BF[2], acc[(MB)+0][2]);                        \
    acc[(MB)+1][2] = mfma_(AF[1], BF[2], acc[(MB)+1][2]);                        \
    acc[(MB)+2][2] = mfma_(AF[2], BF[2], acc[(MB)+2][2]);                        \
    acc[(MB)+3][2] = mfma_(AF[3], BF[2], acc[(MB)+3][2]);                        \
    acc[(MB)+0][3] = mfma_(AF[0], BF[3], acc[(MB)+0][3]);                        \
    acc[(MB)+1][3] = mfma_(AF[1], BF[3], acc[(MB)+1][3]);                        \
    acc[(MB)+2][3] = mfma_(AF[2], BF[3], acc[(MB)+2][3]);                        \
    acc[(MB)+3][3] = mfma_(AF[3], BF[3], acc[(MB)+3][3]); } while (0)

// one K-tile: consume parity P; stage tile T+1 (parity P^1) at byte col offset KSB
#define TILE(P, KSB) do {                                                        \
    /* P1: k0 x m0-3 */                                                          \
    STAGEA((P)^1, 0, KSB);                                                       \
    RDA4(aY, P, 0, 4);                                                           \
    WAITL(4);                                                                    \
    SP1; MFMA16(aX, bb0, 0); SP0;                                                \
    /* P2: k0 x m4-7 */                                                          \
    STAGEB((P)^1, 0, KSB);                                                       \
    VMW4;                                                                        \
    __builtin_amdgcn_s_barrier(); SCHEDB;                                        \
    RDA4(aX, P, 1, 0); RDB4(bb1, P, 1);                                          \
    WAITL(8);                                                                    \
    SP1; MFMA16(aY, bb0, 4); SP0;                                                \
    /* P3: k1 x m0-3 */                                                          \
    STAGEA((P)^1, 1, KSB);                                                       \
    RDA4(aY, P, 1, 4);                                                           \
    WAITL(4);                                                                    \
    SP1; MFMA16(aX, bb1, 0); SP0;                                                \
    /* P4: k1 x m4-7 */                                                          \
    STAGEB((P)^1, 1, KSB);                                                       \
    WAITL(0);                                                                    \
    VMW4;                                                                        \
    __builtin_amdgcn_s_barrier(); SCHEDB;                                        \
    RDA4(aX, (P)^1, 0, 0); RDB4(bb0, (P)^1, 0); SCHEDB;                          \
    SP1; MFMA16(aY, bb1, 4); SP0;                                                \
  } while (0)

__global__ __launch_bounds__(512, 2) void gemm_bt_kernel(
    const __hip_bfloat16* __restrict__ A, const __hip_bfloat16* __restrict__ B,
    float* __restrict__ C, const float* __restrict__ scal, int M, int N, int K) {
  __shared__ __align__(16) char lds[131072];

  // XCD-banded wg map: each XCD gets a 4-row bm band, bn-major -> concurrent 32 blocks
  // share 4 A-panels + 8 B-panels in K-lockstep (L2-resident slices).
  const int nbm = M >> 8, nbn = N >> 8;
  int wg = blockIdx.x, bm, bn;
  if ((nbm & 7) == 0) {
    int band = nbm >> 3;
    int x = wg & 7, c = wg >> 3;
    bm = x * band + (c % band);
    bn = c / band;
  } else {
    bm = wg / nbn; bn = wg % nbn;
  }
  const int brow = bm << 8, bcol = bn << 8;

  const int tid = threadIdx.x;
  const int lane = tid & 63;
  const int wave = tid >> 6;
  const int wm = wave >> 2, wn = wave & 3;

  // staging: thread covers chunk tid (rows 0-127) and tid+512 (rows 128-255) of a
  // 256x32 sub-tile; row = tid>>2, phys slot = tid&3, logical kchunk = phys^((row>>1)&3)
  const int srow = tid >> 2;
  const int slc = (tid & 3) ^ ((tid >> 3) & 3);
  const char* pa = (const char*)(A + (size_t)(brow + srow) * K + slc * 8);
  const char* pb = (const char*)(B + (size_t)(bcol + srow) * K + slc * 8);
  const size_t rowBig = (size_t)128 * K * 2;  // +128 rows in bytes
  char* ldsStA = lds + tid * 16;
  char* ldsStB = lds + 65536 + tid * 16;

  // fragment reads: row R = wbase + 16*mI + (lane&15), kchunk = lane>>4,
  // phys = kchunk ^ ((R>>1)&3) = kchunk ^ ((lane>>1)&3)
  const unsigned ldsBase = (unsigned)(uintptr_t)lds;
  const unsigned xoff = (unsigned)((lane & 15) * 64) +
                        ((((unsigned)(lane >> 4)) ^ (((unsigned)lane >> 1) & 3u)) << 4);
  const unsigned vA = ldsBase + (unsigned)(wm * 8192) + xoff;
  const unsigned vB = ldsBase + 65536u + (unsigned)(wn * 4096) + xoff;

  f32x4 acc[8][4] = {};
  bf16x8 aX[4], aY[4], bb0[4], bb1[4];

  // prologue: stage tile 0 fully (parity 0), publish, issue R1(tile 0)
  STAGEA(0, 0, 0); STAGEB(0, 0, 0); STAGEA(0, 1, 0); STAGEB(0, 1, 0);
  asm volatile("s_waitcnt vmcnt(0)" ::: "memory");
  __syncthreads();
  RDA4(aX, 0, 0, 0); RDB4(bb0, 0, 0); SCHEDB;

  const int nt = K >> 6;  // K-tiles
  for (int it = 0; it < (nt >> 1); ++it) {
    int t0 = it << 1;
    int ks0 = (t0 + 1) * 128;                       // stage tile t0+1
    int ks1 = (t0 + 2 == nt) ? 0 : (t0 + 2) * 128;  // stage tile t0+2 (dead at tail)
    TILE(0, ks0);
    TILE(1, ks1);
  }
  asm volatile("s_waitcnt lgkmcnt(0)" ::: "memory");
  asm volatile("s_waitcnt vmcnt(0)" ::: "memory");

  float gy = 2688.0f / scal[0];
  float gw = 2688.0f / scal[1];
  float alpha = 1.0f / (gy * gw);

  // C/D layout: col = lane&15, row = (lane>>4)*4 + reg
#pragma unroll
  for (int m = 0; m < 8; ++m) {
    int rbase = brow + wm * 128 + m * 16 + ((lane >> 4) << 2);
#pragma unroll
    for (int n = 0; n < 4; ++n) {
      int col = bcol + wn * 64 + n * 16 + (lane & 15);
#pragma unroll
      for (int rg = 0; rg < 4; ++rg) {
        C[(size_t)(rbase + rg) * N + col] = acc[m][n][rg] * alpha;
      }
    }
  }
}

// ---------------- launcher ----------------

extern "C" void kernel_launch(void* const* d_in, const int* in_sizes, int n_in,
                              void* d_out, int out_size, void* d_ws, size_t ws_size,
                              hipStream_t stream) {
  const float* x = (const float*)d_in[0];
  const float* w = (const float*)d_in[1];
  float* out = (float*)d_out;

  int hidden = 1;
  while ((long long)hidden * hidden < (long long)in_sizes[1]) hidden <<= 1;
  int tokens = in_sizes[0] / (2 * hidden);

  char* ws = (char*)d_ws;
  __hip_bfloat16* Aq = (__hip_bfloat16*)ws;
  __hip_bfloat16* Bq = (__hip_bfloat16*)(ws + (size_t)tokens * hidden * 2);
  float* scal = (float*)(ws + (size_t)tokens * hidden * 2 + (size_t)hidden * hidden * 2);

  init_scal_kernel<<<1, 64, 0, stream>>>(scal);
  fused_amax_kernel<<<tokens + hidden, 256, 0, stream>>>(x, w, scal, tokens, hidden);
  fused_quant_kernel<<<tokens + hidden, 256, 0, stream>>>(x, w, Aq, Bq, scal, tokens, hidden);

  int grid = (tokens >> 8) * (hidden >> 8);  // 256x256 tiles
  gemm_bt_kernel<<<grid, 512, 0, stream>>>(Aq, Bq, out, scal, tokens, hidden, hidden);
}

// Round 5
// 414.042 us; speedup vs baseline: 1.5431x; 1.0956x over previous
//
#include <hip/hip_runtime.h>
#include <hip/hip_bf16.h>

typedef __attribute__((ext_vector_type(8))) short bf16x8;
typedef __attribute__((ext_vector_type(4))) float f32x4;

// ---------------- numerics (match jnp reference) ----------------

__device__ __forceinline__ float silu_mul_f(float a, float b) {
  float s = 1.0f / (1.0f + expf(-a));
  return (a * s) * b;
}

// floor(log2(a)) for a>0 via exponent bits (exact for normals)
__device__ __forceinline__ int flog2(float a) {
  return (int)((__float_as_uint(a) >> 23) & 255u) - 127;
}
__device__ __forceinline__ float exp2i(int e) {  // exact 2^e, e in [-126,127]
  return __uint_as_float((unsigned)(e + 127) << 23);
}

__device__ __forceinline__ float round_e4m3_f(float a) {  // a >= 0
  if (!(a > 0.0f)) return 0.0f;
  int e = flog2(a);
  e = e < -6 ? -6 : (e > 8 ? 8 : e);
  float q = rintf(a * exp2i(3 - e)) * exp2i(e - 3);  // rint = half-even, matches jnp.round
  return fminf(q, 448.0f);
}

__device__ __forceinline__ float round_e2m1_f(float x) {
  float a = fminf(fabsf(x), 6.0f);
  if (!(a > 0.0f)) return 0.0f;
  int e = flog2(a);
  e = e < 0 ? 0 : (e > 2 ? 2 : e);
  float q = rintf(a * exp2i(1 - e)) * exp2i(e - 1);  // step = 2^(e-1)
  q = fminf(q, 6.0f);
  return (x < 0.0f) ? -q : q;
}

__global__ void init_scal_kernel(float* scal) {
  if (threadIdx.x < 2) scal[threadIdx.x] = 0.0f;
}

// ---------------- pass 1: grid-stride fused amax (act silu_mul + |w|) ----------------
// unit = one float4. act units cover y (x1,x2 pair loads); w units cover w directly.
// 2048 blocks -> 4096 spread atomics total (vs 12288 same-address before).

__global__ void amax2_kernel(const float* __restrict__ x, const float* __restrict__ w,
                             float* __restrict__ scal, long actU, long wU,
                             int hidden, int hqLog) {
  float mA = 0.0f, mW = 0.0f;
  const long stride = (long)gridDim.x * blockDim.x;
  const long hqm = (1L << hqLog) - 1;
  const long total = actU + wU;
  for (long u = (long)blockIdx.x * blockDim.x + threadIdx.x; u < total; u += stride) {
    if (u < actU) {
      long row = u >> hqLog;
      long c = u & hqm;
      const float* xr = x + ((row * (long)hidden) << 1);
      float4 v1 = ((const float4*)xr)[c];
      float4 v2 = ((const float4*)(xr + hidden))[c];
      mA = fmaxf(mA, fabsf(silu_mul_f(v1.x, v2.x)));
      mA = fmaxf(mA, fabsf(silu_mul_f(v1.y, v2.y)));
      mA = fmaxf(mA, fabsf(silu_mul_f(v1.z, v2.z)));
      mA = fmaxf(mA, fabsf(silu_mul_f(v1.w, v2.w)));
    } else {
      float4 v = ((const float4*)w)[u - actU];
      mW = fmaxf(mW, fmaxf(fmaxf(fabsf(v.x), fabsf(v.y)), fmaxf(fabsf(v.z), fabsf(v.w))));
    }
  }
#pragma unroll
  for (int off = 32; off > 0; off >>= 1) {
    mA = fmaxf(mA, __shfl_xor(mA, off));
    mW = fmaxf(mW, __shfl_xor(mW, off));
  }
  __shared__ float sA[4], sW[4];
  if ((threadIdx.x & 63) == 0) { sA[threadIdx.x >> 6] = mA; sW[threadIdx.x >> 6] = mW; }
  __syncthreads();
  if (threadIdx.x == 0) {
    atomicMax((unsigned int*)(scal + 0),
              __float_as_uint(fmaxf(fmaxf(sA[0], sA[1]), fmaxf(sA[2], sA[3]))));
    atomicMax((unsigned int*)(scal + 1),
              __float_as_uint(fmaxf(fmaxf(sW[0], sW[1]), fmaxf(sW[2], sW[3]))));
  }
}

// ---------------- pass 2: quad-cooperative quant -> dequant bf16 ----------------
// Each lane owns one float4 (coalesced 1KB/wave loads); a 16-elem NVFP4 block = 4
// adjacent lanes; block amax via 2x shfl_xor. Stores ushort4 (8B/lane, contiguous).
// Quads never straddle act/w (actU % 4 == 0) or the tail (totals % 4 == 0).

__global__ void quant2_kernel(const float* __restrict__ x, const float* __restrict__ w,
                              __hip_bfloat16* __restrict__ A, __hip_bfloat16* __restrict__ B,
                              const float* __restrict__ scal, long actU, long wU,
                              int hidden, int hqLog) {
  const float gsA = 2688.0f / scal[0];
  const float gsW = 2688.0f / scal[1];
  const long stride = (long)gridDim.x * blockDim.x;
  const long hqm = (1L << hqLog) - 1;
  const long total = actU + wU;
  for (long u = (long)blockIdx.x * blockDim.x + threadIdx.x; u < total; u += stride) {
    float y0, y1, y2, y3, gs;
    unsigned short* dst;
    if (u < actU) {
      long row = u >> hqLog;
      long c = u & hqm;
      const float* xr = x + ((row * (long)hidden) << 1) + (c << 2);
      float4 v1 = *(const float4*)xr;
      float4 v2 = *(const float4*)(xr + hidden);
      y0 = silu_mul_f(v1.x, v2.x);
      y1 = silu_mul_f(v1.y, v2.y);
      y2 = silu_mul_f(v1.z, v2.z);
      y3 = silu_mul_f(v1.w, v2.w);
      gs = gsA;
      dst = (unsigned short*)A + (u << 2);
    } else {
      float4 v = ((const float4*)w)[u - actU];
      y0 = v.x; y1 = v.y; y2 = v.z; y3 = v.w;
      gs = gsW;
      dst = (unsigned short*)B + ((u - actU) << 2);
    }
    float lm = fmaxf(fmaxf(fabsf(y0), fabsf(y1)), fmaxf(fabsf(y2), fabsf(y3)));
    lm = fmaxf(lm, __shfl_xor(lm, 1));
    lm = fmaxf(lm, __shfl_xor(lm, 2));           // 16-elem block amax across the quad
    float bs = round_e4m3_f(lm / 6.0f * gs);     // op order matches reference
    float r = gs / (bs > 0.0f ? bs : 1.0f);
    ushort4 o;
    o.x = (unsigned short)(__float_as_uint(round_e2m1_f(y0 * r) * bs) >> 16);
    o.y = (unsigned short)(__float_as_uint(round_e2m1_f(y1 * r) * bs) >> 16);
    o.z = (unsigned short)(__float_as_uint(round_e2m1_f(y2 * r) * bs) >> 16);
    o.w = (unsigned short)(__float_as_uint(round_e2m1_f(y3 * r) * bs) >> 16);
    *(ushort4*)dst = o;                          // q*bs <= 6 sig bits -> exact bf16
  }
}

// ---------------- pass 3: 256x256 bf16 GEMM, never-drain pipelined (unchanged R4) ----
// 8 waves (2M x 4N). BK=64 split in two K-halves of 32; LDS regions (16KB each):
// A[parity][khalf] @ parity*32768 + khalf*16384, B same +65536. 4 phases/tile,
// ds-reads pipelined 1 phase ahead (counted lgkmcnt), 1 sub-tile staged per phase,
// vmcnt(4) gates at P2/P4 only -> global_load_lds NEVER drains to 0 in the loop.
// Sub-tile layout: addr = row*64 + phys*16, phys = kchunk ^ ((row>>1)&3) (2-way banks);
// staging sources pre-permuted by the same involution (rule #21).

__device__ __forceinline__ void gload_lds16(const void* g, void* l) {
  __builtin_amdgcn_global_load_lds(
      (const __attribute__((address_space(1))) void*)(uintptr_t)g,
      (__attribute__((address_space(3))) void*)(uintptr_t)l, 16, 0, 0);
}

template <unsigned IMM>
__device__ __forceinline__ bf16x8 lds_read16o(unsigned addr) {
  bf16x8 r;
  asm volatile("ds_read_b128 %0, %1 offset:%c2" : "=&v"(r) : "v"(addr), "i"(IMM));
  return r;
}

__device__ __forceinline__ f32x4 mfma_(bf16x8 a, bf16x8 b, f32x4 c) {
  return __builtin_amdgcn_mfma_f32_16x16x32_bf16(a, b, c, 0, 0, 0);
}

#define SP1 __builtin_amdgcn_s_setprio(1)
#define SP0 __builtin_amdgcn_s_setprio(0)
#define SCHEDB __builtin_amdgcn_sched_barrier(0)
#define WAITL(n) do { asm volatile("s_waitcnt lgkmcnt(" #n ")" ::: "memory"); SCHEDB; } while (0)
#define VMW4 do { asm volatile("s_waitcnt vmcnt(4)" ::: "memory"); } while (0)

#define STAGEA(PP, HH, KSB) do {                                        \
    const char* _s = pa + (KSB) + (HH) * 64;                            \
    gload_lds16(_s, ldsStA + (PP) * 32768 + (HH) * 16384);              \
    gload_lds16(_s + rowBig, ldsStA + (PP) * 32768 + (HH) * 16384 + 8192); } while (0)

#define STAGEB(PP, HH, KSB) do {                                        \
    const char* _s = pb + (KSB) + (HH) * 64;                            \
    gload_lds16(_s, ldsStB + (PP) * 32768 + (HH) * 16384);              \
    gload_lds16(_s + rowBig, ldsStB + (PP) * 32768 + (HH) * 16384 + 8192); } while (0)

#define RDA4(DST, PP, HH, MB) do {                                              \
    DST[0] = lds_read16o<(PP)*32768u + (HH)*16384u + ((MB)+0)*1024u>(vA);       \
    DST[1] = lds_read16o<(PP)*32768u + (HH)*16384u + ((MB)+1)*1024u>(vA);       \
    DST[2] = lds_read16o<(PP)*32768u + (HH)*16384u + ((MB)+2)*1024u>(vA);       \
    DST[3] = lds_read16o<(PP)*32768u + (HH)*16384u + ((MB)+3)*1024u>(vA); } while (0)

#define RDB4(DST, PP, HH) do {                                                  \
    DST[0] = lds_read16o<(PP)*32768u + (HH)*16384u + 0u>(vB);                   \
    DST[1] = lds_read16o<(PP)*32768u + (HH)*16384u + 1024u>(vB);                \
    DST[2] = lds_read16o<(PP)*32768u + (HH)*16384u + 2048u>(vB);                \
    DST[3] = lds_read16o<(PP)*32768u + (HH)*16384u + 3072u>(vB); } while (0)

#define MFMA16(AF, BF, MB) do {                                                  \
    acc[(MB)+0][0] = mfma_(AF[0], BF[0], acc[(MB)+0][0]);                        \
    acc[(MB)+1][0] = mfma_(AF[1], BF[0], acc[(MB)+1][0]);                        \
    acc[(MB)+2][0] = mfma_(AF[2], BF[0], acc[(MB)+2][0]);                        \
    acc[(MB)+3][0] = mfma_(AF[3], BF[0], acc[(MB)+3][0]);                        \
    acc[(MB)+0][1] = mfma_(AF[0], BF[1], acc[(MB)+0][1]);                        \
    acc[(MB)+1][1] = mfma_(AF[1], BF[1], acc[(MB)+1][1]);                        \
    acc[(MB)+2][1] = mfma_(AF[2], BF[1], acc[(MB)+2][1]);                        \
    acc[(MB)+3][1] = mfma_(AF[3], BF[1], acc[(MB)+3][1]);                        \
    acc[(MB)+0][2] = mfma_(AF[0], BF[2], acc[(MB)+0][2]);                        \
    acc[(MB)+1][2] = mfma_(AF[1], BF[2], acc[(MB)+1][2]);                        \
    acc[(MB)+2][2] = mfma_(AF[2], BF[2], acc[(MB)+2][2]);                        \
    acc[(MB)+3][2] = mfma_(AF[3], BF[2], acc[(MB)+3][2]);                        \
    acc[(MB)+0][3] = mfma_(AF[0], BF[3], acc[(MB)+0][3]);                        \
    acc[(MB)+1][3] = mfma_(AF[1], BF[3], acc[(MB)+1][3]);                        \
    acc[(MB)+2][3] = mfma_(AF[2], BF[3], acc[(MB)+2][3]);                        \
    acc[(MB)+3][3] = mfma_(AF[3], BF[3], acc[(MB)+3][3]); } while (0)

#define TILE(P, KSB) do {                                                        \
    STAGEA((P)^1, 0, KSB);                                                       \
    RDA4(aY, P, 0, 4);                                                           \
    WAITL(4);                                                                    \
    SP1; MFMA16(aX, bb0, 0); SP0;                                                \
    STAGEB((P)^1, 0, KSB);                                                       \
    VMW4;                                                                        \
    __builtin_amdgcn_s_barrier(); SCHEDB;                                        \
    RDA4(aX, P, 1, 0); RDB4(bb1, P, 1);                                          \
    WAITL(8);                                                                    \
    SP1; MFMA16(aY, bb0, 4); SP0;                                                \
    STAGEA((P)^1, 1, KSB);                                                       \
    RDA4(aY, P, 1, 4);                                                           \
    WAITL(4);                                                                    \
    SP1; MFMA16(aX, bb1, 0); SP0;                                                \
    STAGEB((P)^1, 1, KSB);                                                       \
    WAITL(0);                                                                    \
    VMW4;                                                                        \
    __builtin_amdgcn_s_barrier(); SCHEDB;                                        \
    RDA4(aX, (P)^1, 0, 0); RDB4(bb0, (P)^1, 0); SCHEDB;                          \
    SP1; MFMA16(aY, bb1, 4); SP0;                                                \
  } while (0)

__global__ __launch_bounds__(512, 2) void gemm_bt_kernel(
    const __hip_bfloat16* __restrict__ A, const __hip_bfloat16* __restrict__ B,
    float* __restrict__ C, const float* __restrict__ scal, int M, int N, int K) {
  __shared__ __align__(16) char lds[131072];

  // XCD-banded wg map: each XCD gets a 4-row bm band, bn-major.
  const int nbm = M >> 8, nbn = N >> 8;
  int wg = blockIdx.x, bm, bn;
  if ((nbm & 7) == 0) {
    int band = nbm >> 3;
    int xcd = wg & 7, c = wg >> 3;
    bm = xcd * band + (c % band);
    bn = c / band;
  } else {
    bm = wg / nbn; bn = wg % nbn;
  }
  const int brow = bm << 8, bcol = bn << 8;

  const int tid = threadIdx.x;
  const int lane = tid & 63;
  const int wave = tid >> 6;
  const int wm = wave >> 2, wn = wave & 3;

  const int srow = tid >> 2;
  const int slc = (tid & 3) ^ ((tid >> 3) & 3);
  const char* pa = (const char*)(A + (size_t)(brow + srow) * K + slc * 8);
  const char* pb = (const char*)(B + (size_t)(bcol + srow) * K + slc * 8);
  const size_t rowBig = (size_t)128 * K * 2;
  char* ldsStA = lds + tid * 16;
  char* ldsStB = lds + 65536 + tid * 16;

  const unsigned ldsBase = (unsigned)(uintptr_t)lds;
  const unsigned xoff = (unsigned)((lane & 15) * 64) +
                        ((((unsigned)(lane >> 4)) ^ (((unsigned)lane >> 1) & 3u)) << 4);
  const unsigned vA = ldsBase + (unsigned)(wm * 8192) + xoff;
  const unsigned vB = ldsBase + 65536u + (unsigned)(wn * 4096) + xoff;

  f32x4 acc[8][4] = {};
  bf16x8 aX[4], aY[4], bb0[4], bb1[4];

  STAGEA(0, 0, 0); STAGEB(0, 0, 0); STAGEA(0, 1, 0); STAGEB(0, 1, 0);
  asm volatile("s_waitcnt vmcnt(0)" ::: "memory");
  __syncthreads();
  RDA4(aX, 0, 0, 0); RDB4(bb0, 0, 0); SCHEDB;

  const int nt = K >> 6;
  for (int it = 0; it < (nt >> 1); ++it) {
    int t0 = it << 1;
    int ks0 = (t0 + 1) * 128;
    int ks1 = (t0 + 2 == nt) ? 0 : (t0 + 2) * 128;
    TILE(0, ks0);
    TILE(1, ks1);
  }
  asm volatile("s_waitcnt lgkmcnt(0)" ::: "memory");
  asm volatile("s_waitcnt vmcnt(0)" ::: "memory");

  float gy = 2688.0f / scal[0];
  float gw = 2688.0f / scal[1];
  float alpha = 1.0f / (gy * gw);

#pragma unroll
  for (int m = 0; m < 8; ++m) {
    int rbase = brow + wm * 128 + m * 16 + ((lane >> 4) << 2);
#pragma unroll
    for (int n = 0; n < 4; ++n) {
      int col = bcol + wn * 64 + n * 16 + (lane & 15);
#pragma unroll
      for (int rg = 0; rg < 4; ++rg) {
        C[(size_t)(rbase + rg) * N + col] = acc[m][n][rg] * alpha;
      }
    }
  }
}

// ---------------- launcher ----------------

extern "C" void kernel_launch(void* const* d_in, const int* in_sizes, int n_in,
                              void* d_out, int out_size, void* d_ws, size_t ws_size,
                              hipStream_t stream) {
  const float* x = (const float*)d_in[0];
  const float* w = (const float*)d_in[1];
  float* out = (float*)d_out;

  int hidden = 1;
  while ((long long)hidden * hidden < (long long)in_sizes[1]) hidden <<= 1;
  int tokens = in_sizes[0] / (2 * hidden);

  char* ws = (char*)d_ws;
  __hip_bfloat16* Aq = (__hip_bfloat16*)ws;
  __hip_bfloat16* Bq = (__hip_bfloat16*)(ws + (size_t)tokens * hidden * 2);
  float* scal = (float*)(ws + (size_t)tokens * hidden * 2 + (size_t)hidden * hidden * 2);

  long actU = (long)tokens * hidden / 4;   // float4 units of y
  long wU = (long)hidden * hidden / 4;     // float4 units of w
  int hqLog = __builtin_ctz((unsigned)(hidden >> 2));

  init_scal_kernel<<<1, 64, 0, stream>>>(scal);
  amax2_kernel<<<2048, 256, 0, stream>>>(x, w, scal, actU, wU, hidden, hqLog);
  quant2_kernel<<<2048, 256, 0, stream>>>(x, w, Aq, Bq, scal, actU, wU, hidden, hqLog);

  int grid = (tokens >> 8) * (hidden >> 8);  // 256x256 tiles
  gemm_bt_kernel<<<grid, 512, 0, stream>>>(Aq, Bq, out, scal, tokens, hidden, hidden);
}

// Round 6
// 395.508 us; speedup vs baseline: 1.6154x; 1.0469x over previous
//
#include <hip/hip_runtime.h>
#include <hip/hip_bf16.h>

typedef __attribute__((ext_vector_type(8))) short bf16x8;
typedef __attribute__((ext_vector_type(4))) float f32x4;
typedef __attribute__((ext_vector_type(16))) float f32x16;

// ---------------- numerics (match jnp reference) ----------------

__device__ __forceinline__ float silu_mul_f(float a, float b) {
  float s = 1.0f / (1.0f + expf(-a));
  return (a * s) * b;
}

__device__ __forceinline__ int flog2(float a) {
  return (int)((__float_as_uint(a) >> 23) & 255u) - 127;
}
__device__ __forceinline__ float exp2i(int e) {
  return __uint_as_float((unsigned)(e + 127) << 23);
}

__device__ __forceinline__ float round_e4m3_f(float a) {  // a >= 0
  if (!(a > 0.0f)) return 0.0f;
  int e = flog2(a);
  e = e < -6 ? -6 : (e > 8 ? 8 : e);
  float q = rintf(a * exp2i(3 - e)) * exp2i(e - 3);
  return fminf(q, 448.0f);
}

__device__ __forceinline__ float round_e2m1_f(float x) {
  float a = fminf(fabsf(x), 6.0f);
  if (!(a > 0.0f)) return 0.0f;
  int e = flog2(a);
  e = e < 0 ? 0 : (e > 2 ? 2 : e);
  float q = rintf(a * exp2i(1 - e)) * exp2i(e - 1);
  q = fminf(q, 6.0f);
  return (x < 0.0f) ? -q : q;
}

__global__ void init_scal_kernel(float* scal) {
  if (threadIdx.x < 2) scal[threadIdx.x] = 0.0f;
}

// ---------------- pass 1: region-split amax, x2 unrolled ----------------

__device__ __forceinline__ float act_unit_max(const float* __restrict__ x, long u,
                                              int hidden, long hqm, int hqLog) {
  long row = u >> hqLog, c = u & hqm;
  const float* xr = x + ((row * (long)hidden) << 1);
  float4 v1 = ((const float4*)xr)[c];
  float4 v2 = ((const float4*)(xr + hidden))[c];
  float m = fmaxf(fabsf(silu_mul_f(v1.x, v2.x)), fabsf(silu_mul_f(v1.y, v2.y)));
  m = fmaxf(m, fmaxf(fabsf(silu_mul_f(v1.z, v2.z)), fabsf(silu_mul_f(v1.w, v2.w))));
  return m;
}

__global__ void amax2_kernel(const float* __restrict__ x, const float* __restrict__ w,
                             float* __restrict__ scal, long actU, long wU,
                             int hidden, int hqLog, int AB) {
  const long hqm = (1L << hqLog) - 1;
  float m = 0.0f;
  int which;
  if ((int)blockIdx.x < AB) {
    which = 0;
    const long stride = (long)AB * blockDim.x;
    long u = (long)blockIdx.x * blockDim.x + threadIdx.x;
    for (; u + stride < actU; u += 2 * stride) {
      float m0 = act_unit_max(x, u, hidden, hqm, hqLog);
      float m1 = act_unit_max(x, u + stride, hidden, hqm, hqLog);
      m = fmaxf(m, fmaxf(m0, m1));
    }
    if (u < actU) m = fmaxf(m, act_unit_max(x, u, hidden, hqm, hqLog));
  } else {
    which = 1;
    const long stride = (long)(gridDim.x - AB) * blockDim.x;
    long u = (long)((int)blockIdx.x - AB) * blockDim.x + threadIdx.x;
    for (; u + stride < wU; u += 2 * stride) {
      float4 v1 = ((const float4*)w)[u];
      float4 v2 = ((const float4*)w)[u + stride];
      float m0 = fmaxf(fmaxf(fabsf(v1.x), fabsf(v1.y)), fmaxf(fabsf(v1.z), fabsf(v1.w)));
      float m1 = fmaxf(fmaxf(fabsf(v2.x), fabsf(v2.y)), fmaxf(fabsf(v2.z), fabsf(v2.w)));
      m = fmaxf(m, fmaxf(m0, m1));
    }
    if (u < wU) {
      float4 v = ((const float4*)w)[u];
      m = fmaxf(m, fmaxf(fmaxf(fabsf(v.x), fabsf(v.y)), fmaxf(fabsf(v.z), fabsf(v.w))));
    }
  }
#pragma unroll
  for (int off = 32; off > 0; off >>= 1) m = fmaxf(m, __shfl_xor(m, off));
  __shared__ float sm[4];
  if ((threadIdx.x & 63) == 0) sm[threadIdx.x >> 6] = m;
  __syncthreads();
  if (threadIdx.x == 0) {
    float mm = fmaxf(fmaxf(sm[0], sm[1]), fmaxf(sm[2], sm[3]));
    atomicMax((unsigned int*)(scal + which), __float_as_uint(mm));
  }
}

// ---------------- pass 2: region-split quad-cooperative quant, x2 unrolled ----------------

__device__ __forceinline__ void quant_unit(float y0, float y1, float y2, float y3,
                                           float gs, unsigned short* dst) {
  float lm = fmaxf(fmaxf(fabsf(y0), fabsf(y1)), fmaxf(fabsf(y2), fabsf(y3)));
  lm = fmaxf(lm, __shfl_xor(lm, 1));
  lm = fmaxf(lm, __shfl_xor(lm, 2));           // 16-elem block amax across the quad
  float bs = round_e4m3_f(lm / 6.0f * gs);
  float r = gs / (bs > 0.0f ? bs : 1.0f);
  ushort4 o;
  o.x = (unsigned short)(__float_as_uint(round_e2m1_f(y0 * r) * bs) >> 16);
  o.y = (unsigned short)(__float_as_uint(round_e2m1_f(y1 * r) * bs) >> 16);
  o.z = (unsigned short)(__float_as_uint(round_e2m1_f(y2 * r) * bs) >> 16);
  o.w = (unsigned short)(__float_as_uint(round_e2m1_f(y3 * r) * bs) >> 16);
  *(ushort4*)dst = o;                          // q*bs <= 6 sig bits -> exact bf16
}

__global__ void quant2_kernel(const float* __restrict__ x, const float* __restrict__ w,
                              __hip_bfloat16* __restrict__ A, __hip_bfloat16* __restrict__ B,
                              const float* __restrict__ scal, long actU, long wU,
                              int hidden, int hqLog, int AB) {
  const long hqm = (1L << hqLog) - 1;
  if ((int)blockIdx.x < AB) {
    const float gs = 2688.0f / scal[0];
    const long stride = (long)AB * blockDim.x;
    long u = (long)blockIdx.x * blockDim.x + threadIdx.x;
    for (; u + stride < actU; u += 2 * stride) {
      long ua = u, ub = u + stride;
      long ra = ua >> hqLog, ca = ua & hqm;
      long rb = ub >> hqLog, cb = ub & hqm;
      const float* xa = x + ((ra * (long)hidden) << 1) + (ca << 2);
      const float* xb = x + ((rb * (long)hidden) << 1) + (cb << 2);
      float4 a1 = *(const float4*)xa;
      float4 a2 = *(const float4*)(xa + hidden);
      float4 b1 = *(const float4*)xb;
      float4 b2 = *(const float4*)(xb + hidden);
      quant_unit(silu_mul_f(a1.x, a2.x), silu_mul_f(a1.y, a2.y),
                 silu_mul_f(a1.z, a2.z), silu_mul_f(a1.w, a2.w),
                 gs, (unsigned short*)A + (ua << 2));
      quant_unit(silu_mul_f(b1.x, b2.x), silu_mul_f(b1.y, b2.y),
                 silu_mul_f(b1.z, b2.z), silu_mul_f(b1.w, b2.w),
                 gs, (unsigned short*)A + (ub << 2));
    }
    if (u < actU) {
      long c = u & hqm;
      const float* xa = x + (((u >> hqLog) * (long)hidden) << 1) + (c << 2);
      float4 v1 = *(const float4*)xa;
      float4 v2 = *(const float4*)(xa + hidden);
      quant_unit(silu_mul_f(v1.x, v2.x), silu_mul_f(v1.y, v2.y),
                 silu_mul_f(v1.z, v2.z), silu_mul_f(v1.w, v2.w),
                 gs, (unsigned short*)A + (u << 2));
    }
  } else {
    const float gs = 2688.0f / scal[1];
    const long stride = (long)(gridDim.x - AB) * blockDim.x;
    long u = (long)((int)blockIdx.x - AB) * blockDim.x + threadIdx.x;
    for (; u + stride < wU; u += 2 * stride) {
      float4 v1 = ((const float4*)w)[u];
      float4 v2 = ((const float4*)w)[u + stride];
      quant_unit(v1.x, v1.y, v1.z, v1.w, gs, (unsigned short*)B + (u << 2));
      quant_unit(v2.x, v2.y, v2.z, v2.w, gs, (unsigned short*)B + ((u + stride) << 2));
    }
    if (u < wU) {
      float4 v = ((const float4*)w)[u];
      quant_unit(v.x, v.y, v.z, v.w, gs, (unsigned short*)B + (u << 2));
    }
  }
}

// ---------------- pass 3: 256x256 bf16 GEMM, 32x32x16 MFMA, never-drain pipeline ----
// R4 skeleton (same LDS regions/staging/vmcnt(4) accounting), inner op switched to
// mfma_f32_32x32x16_bf16 (2495 TF ceiling vs 2075): per phase 8 mfma (was 16), same
// FLOP, same 6 ds_reads -> uniform WAITL(6). Frags: A row=lane&31, k-octet=lane>>5;
// C/D (m74): col=lane&31, row=(reg&3)+8*(reg>>2)+4*(lane>>5).

__device__ __forceinline__ void gload_lds16(const void* g, void* l) {
  __builtin_amdgcn_global_load_lds(
      (const __attribute__((address_space(1))) void*)(uintptr_t)g,
      (__attribute__((address_space(3))) void*)(uintptr_t)l, 16, 0, 0);
}

template <unsigned IMM>
__device__ __forceinline__ bf16x8 lds_read16o(unsigned addr) {
  bf16x8 r;
  asm volatile("ds_read_b128 %0, %1 offset:%c2" : "=&v"(r) : "v"(addr), "i"(IMM));
  return r;
}

__device__ __forceinline__ f32x16 mfma32(bf16x8 a, bf16x8 b, f32x16 c) {
  return __builtin_amdgcn_mfma_f32_32x32x16_bf16(a, b, c, 0, 0, 0);
}

#define SP1 __builtin_amdgcn_s_setprio(1)
#define SP0 __builtin_amdgcn_s_setprio(0)
#define SCHEDB __builtin_amdgcn_sched_barrier(0)
#define WAITL(n) do { asm volatile("s_waitcnt lgkmcnt(" #n ")" ::: "memory"); SCHEDB; } while (0)
#define VMW4 do { asm volatile("s_waitcnt vmcnt(4)" ::: "memory"); } while (0)

#define STAGEA(PP, HH, KSB) do {                                        \
    const char* _s = pa + (KSB) + (HH) * 64;                            \
    gload_lds16(_s, ldsStA + (PP) * 32768 + (HH) * 16384);              \
    gload_lds16(_s + rowBig, ldsStA + (PP) * 32768 + (HH) * 16384 + 8192); } while (0)

#define STAGEB(PP, HH, KSB) do {                                        \
    const char* _s = pb + (KSB) + (HH) * 64;                            \
    gload_lds16(_s, ldsStB + (PP) * 32768 + (HH) * 16384);              \
    gload_lds16(_s + rowBig, ldsStB + (PP) * 32768 + (HH) * 16384 + 8192); } while (0)

// A frag reads: 4 (m=0..3), each 32 rows; base vA0 (ks0) / vA1 (ks1)
#define RDA(DST, PP, HH, KS) do {                                           \
    DST[0] = lds_read16o<(PP)*32768u + (HH)*16384u + 0u>(vA##KS);           \
    DST[1] = lds_read16o<(PP)*32768u + (HH)*16384u + 2048u>(vA##KS);        \
    DST[2] = lds_read16o<(PP)*32768u + (HH)*16384u + 4096u>(vA##KS);        \
    DST[3] = lds_read16o<(PP)*32768u + (HH)*16384u + 6144u>(vA##KS); } while (0)

// B frag reads: 2 (n=0..1)
#define RDB(DST, PP, HH, KS) do {                                           \
    DST[0] = lds_read16o<(PP)*32768u + (HH)*16384u + 0u>(vB##KS);           \
    DST[1] = lds_read16o<(PP)*32768u + (HH)*16384u + 2048u>(vB##KS); } while (0)

#define MFMA8(AF, BF) do {                               \
    acc[0][0] = mfma32(AF[0], BF[0], acc[0][0]);         \
    acc[1][0] = mfma32(AF[1], BF[0], acc[1][0]);         \
    acc[2][0] = mfma32(AF[2], BF[0], acc[2][0]);         \
    acc[3][0] = mfma32(AF[3], BF[0], acc[3][0]);         \
    acc[0][1] = mfma32(AF[0], BF[1], acc[0][1]);         \
    acc[1][1] = mfma32(AF[1], BF[1], acc[1][1]);         \
    acc[2][1] = mfma32(AF[2], BF[1], acc[2][1]);         \
    acc[3][1] = mfma32(AF[3], BF[1], acc[3][1]); } while (0)

// one K-tile (BK=64): consume parity P (khalves 0,1 x ksteps 0,1); stage tile T+1
#define TILE(P, KSB) do {                                                \
    STAGEA((P)^1, 0, KSB);                                               \
    RDA(aB, P, 0, 1); RDB(bB, P, 0, 1);                                  \
    WAITL(6);                                                            \
    SP1; MFMA8(aA, bA); SP0;                                             \
    STAGEB((P)^1, 0, KSB);                                               \
    VMW4;                                                                \
    __builtin_amdgcn_s_barrier(); SCHEDB;                                \
    RDA(aA, P, 1, 0); RDB(bA, P, 1, 0);                                  \
    WAITL(6);                                                            \
    SP1; MFMA8(aB, bB); SP0;                                             \
    STAGEA((P)^1, 1, KSB);                                               \
    RDA(aB, P, 1, 1); RDB(bB, P, 1, 1);                                  \
    WAITL(6);                                                            \
    SP1; MFMA8(aA, bA); SP0;                                             \
    STAGEB((P)^1, 1, KSB);                                               \
    VMW4;                                                                \
    __builtin_amdgcn_s_barrier(); SCHEDB;                                \
    RDA(aA, (P)^1, 0, 0); RDB(bA, (P)^1, 0, 0);                          \
    WAITL(6);                                                            \
    SP1; MFMA8(aB, bB); SP0;                                             \
  } while (0)

__global__ __launch_bounds__(512, 2) void gemm_bt_kernel(
    const __hip_bfloat16* __restrict__ A, const __hip_bfloat16* __restrict__ B,
    float* __restrict__ C, const float* __restrict__ scal, int M, int N, int K) {
  __shared__ __align__(16) char lds[131072];

  // XCD-banded wg map: each XCD gets a 4-row bm band, bn-major.
  const int nbm = M >> 8, nbn = N >> 8;
  int wg = blockIdx.x, bm, bn;
  if ((nbm & 7) == 0) {
    int band = nbm >> 3;
    int xcd = wg & 7, c = wg >> 3;
    bm = xcd * band + (c % band);
    bn = c / band;
  } else {
    bm = wg / nbn; bn = wg % nbn;
  }
  const int brow = bm << 8, bcol = bn << 8;

  const int tid = threadIdx.x;
  const int lane = tid & 63;
  const int wave = tid >> 6;
  const int wm = wave >> 2, wn = wave & 3;

  // staging: row = tid>>2, phys 16B slot = tid&3, logical kchunk = phys^((row>>1)&3)
  const int srow = tid >> 2;
  const int slc = (tid & 3) ^ ((tid >> 3) & 3);
  const char* pa = (const char*)(A + (size_t)(brow + srow) * K + slc * 8);
  const char* pb = (const char*)(B + (size_t)(bcol + srow) * K + slc * 8);
  const size_t rowBig = (size_t)128 * K * 2;
  char* ldsStA = lds + tid * 16;
  char* ldsStB = lds + 65536 + tid * 16;

  // fragment reads: row R = wbase + m*32 + (lane&31); 16B slot = ks*2 + (lane>>5);
  // phys = slot ^ ((R>>1)&3) = slot ^ ((lane>>1)&3)
  const unsigned ldsBase = (unsigned)(uintptr_t)lds;
  const unsigned l31 = (unsigned)(lane & 31);
  const unsigned half = (unsigned)(lane >> 5);
  const unsigned sw = ((unsigned)lane >> 1) & 3u;
  const unsigned rbyte = l31 * 64u;
  const unsigned vA0 = ldsBase + (unsigned)(wm * 8192) + rbyte + ((half ^ sw) << 4);
  const unsigned vA1 = ldsBase + (unsigned)(wm * 8192) + rbyte + (((2u + half) ^ sw) << 4);
  const unsigned vB0 = ldsBase + 65536u + (unsigned)(wn * 4096) + rbyte + ((half ^ sw) << 4);
  const unsigned vB1 = ldsBase + 65536u + (unsigned)(wn * 4096) + rbyte + (((2u + half) ^ sw) << 4);

  f32x16 acc[4][2] = {};
  bf16x8 aA[4], aB[4], bA[2], bB[2];

  // prologue: stage tile 0 (parity 0), publish, issue khalf0-ks0 reads
  STAGEA(0, 0, 0); STAGEB(0, 0, 0); STAGEA(0, 1, 0); STAGEB(0, 1, 0);
  asm volatile("s_waitcnt vmcnt(0)" ::: "memory");
  __syncthreads();
  RDA(aA, 0, 0, 0); RDB(bA, 0, 0, 0); SCHEDB;

  const int nt = K >> 6;
  for (int it = 0; it < (nt >> 1); ++it) {
    int t0 = it << 1;
    int ks0 = (t0 + 1) * 128;
    int ks1 = (t0 + 2 == nt) ? 0 : (t0 + 2) * 128;
    TILE(0, ks0);
    TILE(1, ks1);
  }
  asm volatile("s_waitcnt lgkmcnt(0)" ::: "memory");
  asm volatile("s_waitcnt vmcnt(0)" ::: "memory");

  float gy = 2688.0f / scal[0];
  float gw = 2688.0f / scal[1];
  float alpha = 1.0f / (gy * gw);

  // C/D (32x32): col = lane&31, row = (reg&3) + 8*(reg>>2) + 4*(lane>>5)
#pragma unroll
  for (int mf = 0; mf < 4; ++mf) {
    int rb = brow + wm * 128 + mf * 32 + (int)(half << 2);
#pragma unroll
    for (int nf = 0; nf < 2; ++nf) {
      int col = bcol + wn * 64 + nf * 32 + (int)l31;
#pragma unroll
      for (int g = 0; g < 4; ++g) {
#pragma unroll
        for (int r = 0; r < 4; ++r) {
          C[(size_t)(rb + 8 * g + r) * N + col] = acc[mf][nf][g * 4 + r] * alpha;
        }
      }
    }
  }
}

// ---------------- launcher ----------------

extern "C" void kernel_launch(void* const* d_in, const int* in_sizes, int n_in,
                              void* d_out, int out_size, void* d_ws, size_t ws_size,
                              hipStream_t stream) {
  const float* x = (const float*)d_in[0];
  const float* w = (const float*)d_in[1];
  float* out = (float*)d_out;

  int hidden = 1;
  while ((long long)hidden * hidden < (long long)in_sizes[1]) hidden <<= 1;
  int tokens = in_sizes[0] / (2 * hidden);

  char* ws = (char*)d_ws;
  __hip_bfloat16* Aq = (__hip_bfloat16*)ws;
  __hip_bfloat16* Bq = (__hip_bfloat16*)(ws + (size_t)tokens * hidden * 2);
  float* scal = (float*)(ws + (size_t)tokens * hidden * 2 + (size_t)hidden * hidden * 2);

  long actU = (long)tokens * hidden / 4;   // float4 units of y
  long wU = (long)hidden * hidden / 4;     // float4 units of w
  int hqLog = __builtin_ctz((unsigned)(hidden >> 2));
  int nBlk = 2048;
  int AB = (int)(((long)nBlk * actU) / (actU + wU));  // act/w block split (~2:1)
  AB &= ~3;                                           // keep alignment tidy
  if (AB < 1) AB = 1;
  if (AB > nBlk - 1) AB = nBlk - 1;

  init_scal_kernel<<<1, 64, 0, stream>>>(scal);
  amax2_kernel<<<nBlk, 256, 0, stream>>>(x, w, scal, actU, wU, hidden, hqLog, AB);
  quant2_kernel<<<nBlk, 256, 0, stream>>>(x, w, Aq, Bq, scal, actU, wU, hidden, hqLog, AB);

  int grid = (tokens >> 8) * (hidden >> 8);  // 256x256 tiles
  gemm_bt_kernel<<<grid, 512, 0, stream>>>(Aq, Bq, out, scal, tokens, hidden, hidden);
}